// Round 1
// baseline (821.223 us; speedup 1.0000x reference)
//
#include <hip/hip_runtime.h>

typedef __bf16 bf16x8 __attribute__((ext_vector_type(8)));
typedef __bf16 bf16x4 __attribute__((ext_vector_type(4)));
typedef float  f32x4  __attribute__((ext_vector_type(4)));

__device__ inline float wred_sum(float v){
  #pragma unroll
  for (int d = 1; d < 64; d <<= 1) v += __shfl_xor(v, d, 64);
  return v;
}

__device__ inline float gelu_t(float x){
  const float c0 = 0.7978845608028654f;
  float t = tanhf(c0 * (x + 0.044715f * x * x * x));
  return 0.5f * x * (1.0f + t);
}

// ---------------- transpose + fp32->bf16 convert: in[R][C] f32 -> out[C][R] bf16
__global__ __launch_bounds__(256)
void transpose_cvt(const float* __restrict__ in, __bf16* __restrict__ out, int R, int C){
  long mo = (long)blockIdx.z * R * C;
  in += mo; out += mo;
  __shared__ float t[32][33];
  int r0 = blockIdx.y * 32, c0 = blockIdx.x * 32;
  int tid = threadIdx.x;
  int tr = tid >> 3, tc = (tid & 7) * 4;
  float4 vv = *(const float4*)&in[(long)(r0 + tr) * C + c0 + tc];
  t[tr][tc + 0] = vv.x; t[tr][tc + 1] = vv.y; t[tr][tc + 2] = vv.z; t[tr][tc + 3] = vv.w;
  __syncthreads();
  int oc = tid >> 3, orr = (tid & 7) * 4;
  bf16x4 o4;
  #pragma unroll
  for (int i = 0; i < 4; i++) o4[i] = (__bf16)t[orr + i][oc];
  *(bf16x4*)&out[(long)(c0 + oc) * R + r0 + orr] = o4;
}

// ---------------- adaLN: mods[b][0:6144] = silu(cond[b]) @ adaLN_W
__global__ __launch_bounds__(256)
void adaln_k(const float* __restrict__ cond, const float* __restrict__ W, float* __restrict__ mods){
  int b = blockIdx.y;
  int col = blockIdx.x * 256 + threadIdx.x;
  __shared__ float sc[1024];
  for (int i = threadIdx.x; i < 1024; i += 256){
    float x = cond[b * 1024 + i];
    sc[i] = x / (1.f + expf(-x));
  }
  __syncthreads();
  float acc = 0.f;
  for (int h2 = 0; h2 < 1024; ++h2) acc += sc[h2] * W[(long)h2 * 6144 + col];
  mods[b * 6144 + col] = acc;
}

// ---------------- LayerNorm + modulate -> bf16
__global__ __launch_bounds__(256)
void ln_mod(const float* __restrict__ x, const float* __restrict__ sc, const float* __restrict__ bi,
            const float* __restrict__ mods, int shift_off, int scale_off, __bf16* __restrict__ out){
  int row = blockIdx.x, tid = threadIdx.x, b = row >> 10;
  float4 xv = *(const float4*)&x[(long)row * 1024 + tid * 4];
  float s  = xv.x + xv.y + xv.z + xv.w;
  float s2 = xv.x * xv.x + xv.y * xv.y + xv.z * xv.z + xv.w * xv.w;
  s = wred_sum(s); s2 = wred_sum(s2);
  __shared__ float ssum[4], ssum2[4];
  int w = tid >> 6;
  if ((tid & 63) == 0){ ssum[w] = s; ssum2[w] = s2; }
  __syncthreads();
  s = ssum[0] + ssum[1] + ssum[2] + ssum[3];
  s2 = ssum2[0] + ssum2[1] + ssum2[2] + ssum2[3];
  float mean = s * (1.f / 1024.f);
  float var  = s2 * (1.f / 1024.f) - mean * mean;
  float inv  = rsqrtf(var + 1e-6f);
  const float xa[4] = {xv.x, xv.y, xv.z, xv.w};
  #pragma unroll
  for (int i = 0; i < 4; i++){
    int c = tid * 4 + i;
    float nv = (xa[i] - mean) * inv * sc[c] + bi[c];
    nv = nv * (1.f + mods[b * 6144 + scale_off + c]) + mods[b * 6144 + shift_off + c];
    out[(long)row * 1024 + c] = (__bf16)nv;
  }
}

// ---------------- gate: fp32 LN2+modulate recompute -> logits -> softmax -> top2 -> routing lists
__global__ __launch_bounds__(64)
void gate_k(const float* __restrict__ h, const float* __restrict__ ln2s, const float* __restrict__ ln2b,
            const float* __restrict__ mods, const float* __restrict__ gw,
            int* __restrict__ counts, int* __restrict__ lists, float* __restrict__ wpair){
  int tok = blockIdx.x; int lane = threadIdx.x; int b = tok >> 10;
  float xs[16]; float s = 0.f, s2 = 0.f;
  #pragma unroll
  for (int i = 0; i < 16; i++){
    float xv = h[(long)tok * 1024 + lane + i * 64];
    xs[i] = xv; s += xv; s2 += xv * xv;
  }
  s = wred_sum(s); s2 = wred_sum(s2);
  float mean = s * (1.f / 1024.f);
  float var  = s2 * (1.f / 1024.f) - mean * mean;
  float inv  = rsqrtf(var + 1e-6f);
  float lg[8];
  #pragma unroll
  for (int e = 0; e < 8; e++) lg[e] = 0.f;
  #pragma unroll
  for (int i = 0; i < 16; i++){
    int c = lane + i * 64;
    float nv = (xs[i] - mean) * inv * ln2s[c] + ln2b[c];
    nv = nv * (1.f + mods[b * 6144 + 4096 + c]) + mods[b * 6144 + 3072 + c];
    #pragma unroll
    for (int e = 0; e < 8; e++) lg[e] += nv * gw[e * 1024 + c];
  }
  #pragma unroll
  for (int e = 0; e < 8; e++) lg[e] = wred_sum(lg[e]);
  if (lane == 0){
    float mx = lg[0];
    #pragma unroll
    for (int e = 1; e < 8; e++) mx = fmaxf(mx, lg[e]);
    float p[8], ss = 0.f;
    #pragma unroll
    for (int e = 0; e < 8; e++){ p[e] = expf(lg[e] - mx); ss += p[e]; }
    #pragma unroll
    for (int e = 0; e < 8; e++) p[e] /= ss;
    int i0 = 0; float b0 = p[0];
    #pragma unroll
    for (int e = 1; e < 8; e++) if (p[e] > b0){ b0 = p[e]; i0 = e; }
    int i1 = -1; float b1 = -1.f;
    #pragma unroll
    for (int e = 0; e < 8; e++) if (e != i0 && p[e] > b1){ b1 = p[e]; i1 = e; }
    float dn = b0 + b1 + 1e-20f;
    float w0 = b0 / dn, w1 = b1 / dn;
    int s0 = atomicAdd(&counts[i0], 1); lists[i0 * 4096 + s0] = tok * 2;     wpair[tok * 2]     = w0;
    int s1 = atomicAdd(&counts[i1], 1); lists[i1 * 4096 + s1] = tok * 2 + 1; wpair[tok * 2 + 1] = w1;
  }
}

// ---------------- flash attention: 64 q-rows per block, 4 waves x 16 rows
__global__ __launch_bounds__(256)
void attn_k(const __bf16* __restrict__ qg, const __bf16* __restrict__ kg,
            const __bf16* __restrict__ vg, __bf16* __restrict__ og){
  int bh = blockIdx.y; int bb = bh >> 4, hn = bh & 15;
  int q0 = blockIdx.x * 64;
  long tokbase = (long)bb * 1024;
  int hd0 = hn * 64;
  int tid = threadIdx.x; int w = tid >> 6; int lane = tid & 63;

  __shared__ __bf16 Ks[64][72];
  __shared__ __bf16 Vt[64][72];
  __shared__ __bf16 Ps[4][16][72];

  long qrow = tokbase + q0 + w * 16 + (lane & 15);
  bf16x8 qf0 = *(const bf16x8*)&qg[qrow * 1024 + hd0 + (lane >> 4) * 8];
  bf16x8 qf1 = *(const bf16x8*)&qg[qrow * 1024 + hd0 + 32 + (lane >> 4) * 8];

  float m_r[4], l_r[4];
  f32x4 oa[4];
  #pragma unroll
  for (int r = 0; r < 4; r++){ m_r[r] = -1e30f; l_r[r] = 0.f; }
  #pragma unroll
  for (int hb = 0; hb < 4; hb++) oa[hb] = (f32x4){0.f, 0.f, 0.f, 0.f};

  for (int t = 0; t < 16; t++){
    long kvbase = tokbase + t * 64;
    #pragma unroll
    for (int p = 0; p < 2; p++){
      int r = (tid >> 3) + p * 32;
      int c = (tid & 7) * 8;
      *(bf16x8*)&Ks[r][c] = *(const bf16x8*)&kg[(kvbase + r) * 1024 + hd0 + c];
      bf16x8 vv = *(const bf16x8*)&vg[(kvbase + r) * 1024 + hd0 + c];
      #pragma unroll
      for (int i = 0; i < 8; i++) Vt[c + i][r] = vv[i];
    }
    __syncthreads();
    f32x4 sf[4];
    #pragma unroll
    for (int cb = 0; cb < 4; cb++){
      bf16x8 kf0 = *(const bf16x8*)&Ks[cb * 16 + (lane & 15)][(lane >> 4) * 8];
      bf16x8 kf1 = *(const bf16x8*)&Ks[cb * 16 + (lane & 15)][32 + (lane >> 4) * 8];
      f32x4 sacc = (f32x4){0.f, 0.f, 0.f, 0.f};
      sacc = __builtin_amdgcn_mfma_f32_16x16x32_bf16(qf0, kf0, sacc, 0, 0, 0);
      sacc = __builtin_amdgcn_mfma_f32_16x16x32_bf16(qf1, kf1, sacc, 0, 0, 0);
      #pragma unroll
      for (int r = 0; r < 4; r++) sacc[r] *= 0.125f;
      sf[cb] = sacc;
    }
    #pragma unroll
    for (int r = 0; r < 4; r++){
      float mx = fmaxf(fmaxf(sf[0][r], sf[1][r]), fmaxf(sf[2][r], sf[3][r]));
      #pragma unroll
      for (int d = 1; d < 16; d <<= 1) mx = fmaxf(mx, __shfl_xor(mx, d, 64));
      float mn = fmaxf(m_r[r], mx);
      float fr = expf(m_r[r] - mn);
      m_r[r] = mn;
      float ps = 0.f;
      #pragma unroll
      for (int cb = 0; cb < 4; cb++){
        float pe = expf(sf[cb][r] - mn);
        sf[cb][r] = pe;
        ps += pe;
      }
      #pragma unroll
      for (int d = 1; d < 16; d <<= 1) ps += __shfl_xor(ps, d, 64);
      l_r[r] = l_r[r] * fr + ps;
      #pragma unroll
      for (int hb = 0; hb < 4; hb++) oa[hb][r] *= fr;
    }
    #pragma unroll
    for (int cb = 0; cb < 4; cb++)
      #pragma unroll
      for (int r = 0; r < 4; r++)
        Ps[w][(lane >> 4) * 4 + r][cb * 16 + (lane & 15)] = (__bf16)sf[cb][r];
    __syncthreads();
    bf16x8 pf0 = *(const bf16x8*)&Ps[w][lane & 15][(lane >> 4) * 8];
    bf16x8 pf1 = *(const bf16x8*)&Ps[w][lane & 15][32 + (lane >> 4) * 8];
    #pragma unroll
    for (int hb = 0; hb < 4; hb++){
      bf16x8 vf0 = *(const bf16x8*)&Vt[hb * 16 + (lane & 15)][(lane >> 4) * 8];
      bf16x8 vf1 = *(const bf16x8*)&Vt[hb * 16 + (lane & 15)][32 + (lane >> 4) * 8];
      oa[hb] = __builtin_amdgcn_mfma_f32_16x16x32_bf16(pf0, vf0, oa[hb], 0, 0, 0);
      oa[hb] = __builtin_amdgcn_mfma_f32_16x16x32_bf16(pf1, vf1, oa[hb], 0, 0, 0);
    }
    __syncthreads();
  }
  #pragma unroll
  for (int hb = 0; hb < 4; hb++)
    #pragma unroll
    for (int r = 0; r < 4; r++){
      long row = tokbase + q0 + w * 16 + (lane >> 4) * 4 + r;
      float val = oa[hb][r] / l_r[r];
      og[row * 1024 + hd0 + hb * 16 + (lane & 15)] = (__bf16)val;
    }
}

// ---------------- generic bf16 MFMA GEMM: C[M,N] = A[M,K] @ Bt[N,K]^T
// EPI: 0=store bf16, 1=gelu->bf16, 2=h=resid+gate*acc (f32), 3=store f32, 4=atomicAdd(w*acc)
// GMODE: 0=linear rows, 1=expert GEMM1 (src=pair>>1, dst=pair), 2=expert GEMM2 (src=pair, dst token=pair>>1)
template<int EPI, int GMODE>
__global__ __launch_bounds__(256)
void gemm_k(const __bf16* __restrict__ A, int lda,
            const __bf16* __restrict__ Bt, int K, long bstride,
            const int* __restrict__ lists, const int* __restrict__ counts,
            __bf16* __restrict__ outb, int ldo,
            float* __restrict__ outf,
            const float* __restrict__ resid,
            const float* __restrict__ mods, int mod_off,
            const float* __restrict__ wpair){
  int e = blockIdx.z;
  int cnt = 1 << 30;
  const int* list = nullptr;
  if (GMODE){
    cnt = counts[e];
    list = lists + e * 4096;
    Bt += (long)e * bstride;
  }
  int row0 = blockIdx.y * 128;
  if (GMODE && row0 >= cnt) return;
  int n0 = blockIdx.x * 128;
  int tid = threadIdx.x;
  int lane = tid & 63, w = tid >> 6;
  int wr = (w >> 1) * 64, wc = (w & 1) * 64;

  __shared__ __bf16 As[128][72];
  __shared__ __bf16 Bs[128][72];

  f32x4 acc[4][4];
  #pragma unroll
  for (int m = 0; m < 4; m++)
    #pragma unroll
    for (int n = 0; n < 4; n++) acc[m][n] = (f32x4){0.f, 0.f, 0.f, 0.f};

  int sr = tid >> 3;
  int scol = (tid & 7) * 8;
  int arow[4];
  #pragma unroll
  for (int p = 0; p < 4; p++){
    int gr = row0 + p * 32 + sr;
    int src;
    if (GMODE == 0) src = gr;
    else if (gr < cnt){ int pv = list[gr]; src = (GMODE == 1) ? (pv >> 1) : pv; }
    else src = -1;
    arow[p] = src;
  }
  const bf16x8 z8 = (bf16x8){(__bf16)0.f,(__bf16)0.f,(__bf16)0.f,(__bf16)0.f,
                             (__bf16)0.f,(__bf16)0.f,(__bf16)0.f,(__bf16)0.f};
  const int nk = K / 64;
  for (int kt = 0; kt < nk; ++kt){
    int k0 = kt * 64;
    #pragma unroll
    for (int p = 0; p < 4; p++){
      bf16x8 av = (arow[p] >= 0) ? *(const bf16x8*)&A[(long)arow[p] * lda + k0 + scol] : z8;
      *(bf16x8*)&As[p * 32 + sr][scol] = av;
      bf16x8 bv = *(const bf16x8*)&Bt[(long)(n0 + p * 32 + sr) * K + k0 + scol];
      *(bf16x8*)&Bs[p * 32 + sr][scol] = bv;
    }
    __syncthreads();
    #pragma unroll
    for (int ks = 0; ks < 2; ++ks){
      bf16x8 af[4], bfr[4];
      #pragma unroll
      for (int m = 0; m < 4; m++) af[m]  = *(const bf16x8*)&As[wr + m * 16 + (lane & 15)][ks * 32 + (lane >> 4) * 8];
      #pragma unroll
      for (int n = 0; n < 4; n++) bfr[n] = *(const bf16x8*)&Bs[wc + n * 16 + (lane & 15)][ks * 32 + (lane >> 4) * 8];
      #pragma unroll
      for (int m = 0; m < 4; m++)
        #pragma unroll
        for (int n = 0; n < 4; n++)
          acc[m][n] = __builtin_amdgcn_mfma_f32_16x16x32_bf16(af[m], bfr[n], acc[m][n], 0, 0, 0);
    }
    __syncthreads();
  }
  #pragma unroll
  for (int m = 0; m < 4; m++){
    #pragma unroll
    for (int r = 0; r < 4; r++){
      int rl = wr + m * 16 + (lane >> 4) * 4 + r;
      int grow = row0 + rl;
      if (GMODE && grow >= cnt) continue;
      #pragma unroll
      for (int n = 0; n < 4; n++){
        int col = n0 + wc + n * 16 + (lane & 15);
        float v = acc[m][n][r];
        if (EPI == 0){
          outb[(long)grow * ldo + col] = (__bf16)v;
        } else if (EPI == 1){
          int dst = (GMODE == 1) ? list[grow] : grow;
          outb[(long)dst * ldo + col] = (__bf16)gelu_t(v);
        } else if (EPI == 2){
          int b = grow >> 10;
          outf[(long)grow * 1024 + col] = resid[(long)grow * 1024 + col] + mods[b * 6144 + mod_off + col] * v;
        } else if (EPI == 3){
          outf[(long)grow * 1024 + col] = v;
        } else if (EPI == 4){
          int pv = list[grow];
          atomicAdd(&outf[(long)(pv >> 1) * 1024 + col], wpair[pv] * v);
        }
      }
    }
  }
}

// ---------------- final: out = h + gate_mlp * y
__global__ __launch_bounds__(256)
void final_k(const float* __restrict__ h, const float* __restrict__ y,
             const float* __restrict__ mods, float* __restrict__ out){
  int i = blockIdx.x * 256 + threadIdx.x;
  long base = (long)i * 4;
  int row = (int)(base >> 10); int b = row >> 10; int c = (int)(base & 1023);
  float4 hv = *(const float4*)&h[base];
  float4 yv = *(const float4*)&y[base];
  const float* g = &mods[b * 6144 + 5120 + c];
  float4 o;
  o.x = hv.x + g[0] * yv.x;
  o.y = hv.y + g[1] * yv.y;
  o.z = hv.z + g[2] * yv.z;
  o.w = hv.w + g[3] * yv.w;
  *(float4*)&out[base] = o;
}

extern "C" void kernel_launch(void* const* d_in, const int* in_sizes, int n_in,
                              void* d_out, int out_size, void* d_ws, size_t ws_size,
                              hipStream_t stream){
  const float* hidden = (const float*)d_in[0];
  const float* cond   = (const float*)d_in[1];
  const float* adaW   = (const float*)d_in[2];
  const float* ln1s   = (const float*)d_in[3];
  const float* ln1b   = (const float*)d_in[4];
  const float* ln2s   = (const float*)d_in[5];
  const float* ln2b   = (const float*)d_in[6];
  const float* Wq     = (const float*)d_in[7];
  const float* Wk     = (const float*)d_in[8];
  const float* Wv     = (const float*)d_in[9];
  const float* Wo     = (const float*)d_in[10];
  const float* gatek  = (const float*)d_in[11];
  const float* We1    = (const float*)d_in[12];
  const float* We2    = (const float*)d_in[13];
  const float* Ws1    = (const float*)d_in[14];
  const float* Ws2    = (const float*)d_in[15];
  float* out = (float*)d_out;

  const size_t MB = 1024 * 1024;
  char* W = (char*)d_ws;
  size_t off = 0;
  auto take = [&](size_t b) -> void* {
    void* p = W + off;
    off += (b + 255) & ~((size_t)255);
    return p;
  };
  float*  mods   = (float*) take(4 * 6144 * sizeof(float));
  __bf16* WqT    = (__bf16*)take(2 * MB);
  __bf16* WkT    = (__bf16*)take(2 * MB);
  __bf16* WvT    = (__bf16*)take(2 * MB);
  __bf16* WoT    = (__bf16*)take(2 * MB);
  __bf16* Ws1T   = (__bf16*)take(4 * MB);
  __bf16* Ws2T   = (__bf16*)take(4 * MB);
  __bf16* We1T   = (__bf16*)take(16 * MB);
  __bf16* We2T   = (__bf16*)take(16 * MB);
  __bf16* n1     = (__bf16*)take(8 * MB);
  __bf16* qb     = (__bf16*)take(8 * MB);
  __bf16* kb     = (__bf16*)take(8 * MB);
  __bf16* vb     = (__bf16*)take(8 * MB);
  __bf16* ab     = (__bf16*)take(8 * MB);
  float*  hb     = (float*) take(16 * MB);
  __bf16* n2     = (__bf16*)take(8 * MB);
  float*  yb     = (float*) take(16 * MB);
  int*    counts = (int*)   take(256);
  int*    lists  = (int*)   take(8 * 4096 * 4);
  float*  wpair  = (float*) take(8192 * 4);
  __bf16* SH = qb;  // aliases q+k (16 MB), dead after attention
  __bf16* EH = vb;  // aliases v+attn_out (16 MB), dead after Wo GEMM

  dim3 blk(256);

  hipMemsetAsync(counts, 0, 32, stream);

  // weight transposes (fp32 -> bf16 [N][K])
  transpose_cvt<<<dim3(32, 32, 1), blk, 0, stream>>>(Wq,  WqT,  1024, 1024);
  transpose_cvt<<<dim3(32, 32, 1), blk, 0, stream>>>(Wk,  WkT,  1024, 1024);
  transpose_cvt<<<dim3(32, 32, 1), blk, 0, stream>>>(Wv,  WvT,  1024, 1024);
  transpose_cvt<<<dim3(32, 32, 1), blk, 0, stream>>>(Wo,  WoT,  1024, 1024);
  transpose_cvt<<<dim3(64, 32, 1), blk, 0, stream>>>(Ws1, Ws1T, 1024, 2048);
  transpose_cvt<<<dim3(32, 64, 1), blk, 0, stream>>>(Ws2, Ws2T, 2048, 1024);
  transpose_cvt<<<dim3(32, 32, 8), blk, 0, stream>>>(We1, We1T, 1024, 1024);
  transpose_cvt<<<dim3(32, 32, 8), blk, 0, stream>>>(We2, We2T, 1024, 1024);

  adaln_k<<<dim3(24, 4), blk, 0, stream>>>(cond, adaW, mods);

  // LN1 + modulate (shift_msa@0, scale_msa@1024)
  ln_mod<<<4096, blk, 0, stream>>>(hidden, ln1s, ln1b, mods, 0, 1024, n1);

  // QKV projections
  gemm_k<0, 0><<<dim3(8, 32, 1), blk, 0, stream>>>(n1, 1024, WqT, 1024, 0, nullptr, nullptr, qb, 1024, nullptr, nullptr, nullptr, 0, nullptr);
  gemm_k<0, 0><<<dim3(8, 32, 1), blk, 0, stream>>>(n1, 1024, WkT, 1024, 0, nullptr, nullptr, kb, 1024, nullptr, nullptr, nullptr, 0, nullptr);
  gemm_k<0, 0><<<dim3(8, 32, 1), blk, 0, stream>>>(n1, 1024, WvT, 1024, 0, nullptr, nullptr, vb, 1024, nullptr, nullptr, nullptr, 0, nullptr);

  attn_k<<<dim3(16, 64, 1), blk, 0, stream>>>(qb, kb, vb, ab);

  // h = hidden + gate_msa (mods@2048) * (attn @ Wo)
  gemm_k<2, 0><<<dim3(8, 32, 1), blk, 0, stream>>>(ab, 1024, WoT, 1024, 0, nullptr, nullptr, nullptr, 0, hb, hidden, mods, 2048, nullptr);

  // LN2 + modulate (shift_mlp@3072, scale_mlp@4096)
  ln_mod<<<4096, blk, 0, stream>>>(hb, ln2s, ln2b, mods, 3072, 4096, n2);

  // MoE gate (fp32 recompute of normed2 from h)
  gate_k<<<4096, 64, 0, stream>>>(hb, ln2s, ln2b, mods, gatek, counts, lists, wpair);

  // shared experts: SH = gelu(n2 @ Ws1); y = SH @ Ws2
  gemm_k<1, 0><<<dim3(16, 32, 1), blk, 0, stream>>>(n2, 1024, Ws1T, 1024, 0, nullptr, nullptr, SH, 2048, nullptr, nullptr, nullptr, 0, nullptr);
  gemm_k<3, 0><<<dim3(8, 32, 1), blk, 0, stream>>>(SH, 2048, Ws2T, 2048, 0, nullptr, nullptr, nullptr, 0, yb, nullptr, nullptr, 0, nullptr);

  // routed experts (top-2 only): EH = gelu(gather(n2) @ We1[e]); y += w * (EH @ We2[e])
  gemm_k<1, 1><<<dim3(8, 32, 8), blk, 0, stream>>>(n2, 1024, We1T, 1024, 1048576, lists, counts, EH, 1024, nullptr, nullptr, nullptr, 0, nullptr);
  gemm_k<4, 2><<<dim3(8, 32, 8), blk, 0, stream>>>(EH, 1024, We2T, 1024, 1048576, lists, counts, nullptr, 0, yb, nullptr, nullptr, 0, wpair);

  // out = h + gate_mlp (mods@5120) * y
  final_k<<<4096, blk, 0, stream>>>(hb, yb, mods, out);

  (void)in_sizes; (void)n_in; (void)out_size; (void)ws_size;
}

// Round 2
// 667.615 us; speedup vs baseline: 1.2301x; 1.2301x over previous
//
#include <hip/hip_runtime.h>

typedef __bf16 bf16x8 __attribute__((ext_vector_type(8)));
typedef __bf16 bf16x4 __attribute__((ext_vector_type(4)));
typedef float  f32x4  __attribute__((ext_vector_type(4)));

__device__ inline float wred_sum(float v){
  #pragma unroll
  for (int d = 1; d < 64; d <<= 1) v += __shfl_xor(v, d, 64);
  return v;
}

__device__ inline float gelu_t(float x){
  const float c0 = 0.7978845608028654f;
  float t = tanhf(c0 * (x + 0.044715f * x * x * x));
  return 0.5f * x * (1.0f + t);
}

__device__ __forceinline__ void gload_lds16(const __bf16* g, __bf16* l){
  __builtin_amdgcn_global_load_lds((const __attribute__((address_space(1))) void*)g,
                                   (__attribute__((address_space(3))) void*)l, 16, 0, 0);
}

// ---------------- transpose + fp32->bf16 convert: in[R][C] f32 -> out[C][R] bf16
__global__ __launch_bounds__(256)
void transpose_cvt(const float* __restrict__ in, __bf16* __restrict__ out, int R, int C){
  long mo = (long)blockIdx.z * R * C;
  in += mo; out += mo;
  __shared__ float t[32][33];
  int r0 = blockIdx.y * 32, c0 = blockIdx.x * 32;
  int tid = threadIdx.x;
  int tr = tid >> 3, tc = (tid & 7) * 4;
  float4 vv = *(const float4*)&in[(long)(r0 + tr) * C + c0 + tc];
  t[tr][tc + 0] = vv.x; t[tr][tc + 1] = vv.y; t[tr][tc + 2] = vv.z; t[tr][tc + 3] = vv.w;
  __syncthreads();
  int oc = tid >> 3, orr = (tid & 7) * 4;
  bf16x4 o4;
  #pragma unroll
  for (int i = 0; i < 4; i++) o4[i] = (__bf16)t[orr + i][oc];
  *(bf16x4*)&out[(long)(c0 + oc) * R + r0 + orr] = o4;
}

// ---------------- adaLN: mods[b][0:6144] += partial over h2-chunk (split-K, fp32 atomics)
__global__ __launch_bounds__(256)
void adaln_k(const float* __restrict__ cond, const float* __restrict__ W, float* __restrict__ mods){
  int b = blockIdx.y, z = blockIdx.z;
  int col = (blockIdx.x * 256 + threadIdx.x) * 4;
  __shared__ float sc[256];
  int h2 = z * 256 + threadIdx.x;
  float x = cond[b * 1024 + h2];
  sc[threadIdx.x] = x / (1.f + expf(-x));
  __syncthreads();
  float a0 = 0.f, a1 = 0.f, a2 = 0.f, a3 = 0.f;
  #pragma unroll 4
  for (int i = 0; i < 256; i++){
    float s = sc[i];
    float4 wv = *(const float4*)&W[(long)(z * 256 + i) * 6144 + col];
    a0 += s * wv.x; a1 += s * wv.y; a2 += s * wv.z; a3 += s * wv.w;
  }
  atomicAdd(&mods[b * 6144 + col + 0], a0);
  atomicAdd(&mods[b * 6144 + col + 1], a1);
  atomicAdd(&mods[b * 6144 + col + 2], a2);
  atomicAdd(&mods[b * 6144 + col + 3], a3);
}

// ---------------- LayerNorm + modulate -> bf16
__global__ __launch_bounds__(256)
void ln_mod(const float* __restrict__ x, const float* __restrict__ sc, const float* __restrict__ bi,
            const float* __restrict__ mods, int shift_off, int scale_off, __bf16* __restrict__ out){
  int row = blockIdx.x, tid = threadIdx.x, b = row >> 10;
  float4 xv = *(const float4*)&x[(long)row * 1024 + tid * 4];
  float s  = xv.x + xv.y + xv.z + xv.w;
  float s2 = xv.x * xv.x + xv.y * xv.y + xv.z * xv.z + xv.w * xv.w;
  s = wred_sum(s); s2 = wred_sum(s2);
  __shared__ float ssum[4], ssum2[4];
  int w = tid >> 6;
  if ((tid & 63) == 0){ ssum[w] = s; ssum2[w] = s2; }
  __syncthreads();
  s = ssum[0] + ssum[1] + ssum[2] + ssum[3];
  s2 = ssum2[0] + ssum2[1] + ssum2[2] + ssum2[3];
  float mean = s * (1.f / 1024.f);
  float var  = s2 * (1.f / 1024.f) - mean * mean;
  float inv  = rsqrtf(var + 1e-6f);
  const float xa[4] = {xv.x, xv.y, xv.z, xv.w};
  #pragma unroll
  for (int i = 0; i < 4; i++){
    int c = tid * 4 + i;
    float nv = (xa[i] - mean) * inv * sc[c] + bi[c];
    nv = nv * (1.f + mods[b * 6144 + scale_off + c]) + mods[b * 6144 + shift_off + c];
    out[(long)row * 1024 + c] = (__bf16)nv;
  }
}

// ---------------- gate: 4 tokens/block, gw in LDS, fp32 LN2 recompute, top2 routing
__global__ __launch_bounds__(256)
void gate_k(const float* __restrict__ h, const float* __restrict__ ln2s, const float* __restrict__ ln2b,
            const float* __restrict__ mods, const float* __restrict__ gw,
            int* __restrict__ counts, int* __restrict__ lists, float* __restrict__ wpair){
  __shared__ float gws[8192];
  int tid = threadIdx.x;
  #pragma unroll
  for (int i = 0; i < 8; i++){
    int idx = tid + i * 256;
    *(float4*)&gws[idx * 4] = *(const float4*)&gw[idx * 4];
  }
  __syncthreads();
  int wv = tid >> 6, lane = tid & 63;
  int tok = blockIdx.x * 4 + wv;
  int b = tok >> 10;
  float4 xv[4]; float s = 0.f, s2 = 0.f;
  #pragma unroll
  for (int ch = 0; ch < 4; ch++){
    float4 v = *(const float4*)&h[(long)tok * 1024 + ch * 256 + lane * 4];
    xv[ch] = v;
    s  += v.x + v.y + v.z + v.w;
    s2 += v.x * v.x + v.y * v.y + v.z * v.z + v.w * v.w;
  }
  s = wred_sum(s); s2 = wred_sum(s2);
  float mean = s * (1.f / 1024.f);
  float var  = s2 * (1.f / 1024.f) - mean * mean;
  float inv  = rsqrtf(var + 1e-6f);
  float lg[8];
  #pragma unroll
  for (int e = 0; e < 8; e++) lg[e] = 0.f;
  #pragma unroll
  for (int ch = 0; ch < 4; ch++){
    int c = ch * 256 + lane * 4;
    float4 s4  = *(const float4*)&ln2s[c];
    float4 b4  = *(const float4*)&ln2b[c];
    float4 sc4 = *(const float4*)&mods[b * 6144 + 4096 + c];
    float4 sh4 = *(const float4*)&mods[b * 6144 + 3072 + c];
    float n0 = ((xv[ch].x - mean) * inv * s4.x + b4.x) * (1.f + sc4.x) + sh4.x;
    float n1 = ((xv[ch].y - mean) * inv * s4.y + b4.y) * (1.f + sc4.y) + sh4.y;
    float n2 = ((xv[ch].z - mean) * inv * s4.z + b4.z) * (1.f + sc4.z) + sh4.z;
    float n3 = ((xv[ch].w - mean) * inv * s4.w + b4.w) * (1.f + sc4.w) + sh4.w;
    #pragma unroll
    for (int e = 0; e < 8; e++){
      float4 g4 = *(const float4*)&gws[e * 1024 + c];
      lg[e] += n0 * g4.x + n1 * g4.y + n2 * g4.z + n3 * g4.w;
    }
  }
  #pragma unroll
  for (int e = 0; e < 8; e++) lg[e] = wred_sum(lg[e]);
  if (lane == 0){
    float mx = lg[0];
    #pragma unroll
    for (int e = 1; e < 8; e++) mx = fmaxf(mx, lg[e]);
    float p[8], ss = 0.f;
    #pragma unroll
    for (int e = 0; e < 8; e++){ p[e] = expf(lg[e] - mx); ss += p[e]; }
    #pragma unroll
    for (int e = 0; e < 8; e++) p[e] /= ss;
    int i0 = 0; float b0 = p[0];
    #pragma unroll
    for (int e = 1; e < 8; e++) if (p[e] > b0){ b0 = p[e]; i0 = e; }
    int i1 = -1; float b1 = -1.f;
    #pragma unroll
    for (int e = 0; e < 8; e++) if (e != i0 && p[e] > b1){ b1 = p[e]; i1 = e; }
    float dn = b0 + b1 + 1e-20f;
    int s0 = atomicAdd(&counts[i0], 1); lists[i0 * 4096 + s0] = tok * 2;     wpair[tok * 2]     = b0 / dn;
    int s1 = atomicAdd(&counts[i1], 1); lists[i1 * 4096 + s1] = tok * 2 + 1; wpair[tok * 2 + 1] = b1 / dn;
  }
}

// ---------------- flash attention over fused qkv [4096][3072]
__global__ __launch_bounds__(256)
void attn_k(const __bf16* __restrict__ qkv, __bf16* __restrict__ og){
  int bh = blockIdx.y; int bb = bh >> 4, hn = bh & 15;
  int q0 = blockIdx.x * 64;
  long tokbase = (long)bb * 1024;
  int hd0 = hn * 64;
  int tid = threadIdx.x; int w = tid >> 6; int lane = tid & 63;

  __shared__ __bf16 Ks[64][72];
  __shared__ __bf16 Vt[64][72];
  __shared__ __bf16 Ps[4][16][72];

  long qrow = tokbase + q0 + w * 16 + (lane & 15);
  bf16x8 qf0 = *(const bf16x8*)&qkv[qrow * 3072 + hd0 + (lane >> 4) * 8];
  bf16x8 qf1 = *(const bf16x8*)&qkv[qrow * 3072 + hd0 + 32 + (lane >> 4) * 8];
  #pragma unroll
  for (int i = 0; i < 8; i++){  // fold 1/sqrt(64) into q (exact in bf16)
    qf0[i] = (__bf16)((float)qf0[i] * 0.125f);
    qf1[i] = (__bf16)((float)qf1[i] * 0.125f);
  }

  float m_r[4], l_r[4];
  f32x4 oa[4];
  #pragma unroll
  for (int r = 0; r < 4; r++){ m_r[r] = -1e30f; l_r[r] = 0.f; }
  #pragma unroll
  for (int hb = 0; hb < 4; hb++) oa[hb] = (f32x4){0.f, 0.f, 0.f, 0.f};

  int dcol = tid & 63, rblk = tid >> 6;
  for (int t = 0; t < 16; t++){
    long kvbase = tokbase + t * 64;
    #pragma unroll
    for (int p = 0; p < 2; p++){
      int r = (tid >> 3) + p * 32;
      int c = (tid & 7) * 8;
      *(bf16x8*)&Ks[r][c] = *(const bf16x8*)&qkv[(kvbase + r) * 3072 + 1024 + hd0 + c];
    }
    // V: each lane loads a column (coalesced across lanes), writes contiguous Vt row chunk
    bf16x8 col0, col1;
    #pragma unroll
    for (int i = 0; i < 8; i++)
      col0[i] = qkv[(kvbase + rblk * 16 + i) * 3072 + 2048 + hd0 + dcol];
    #pragma unroll
    for (int i = 0; i < 8; i++)
      col1[i] = qkv[(kvbase + rblk * 16 + 8 + i) * 3072 + 2048 + hd0 + dcol];
    *(bf16x8*)&Vt[dcol][rblk * 16]     = col0;
    *(bf16x8*)&Vt[dcol][rblk * 16 + 8] = col1;
    __syncthreads();
    f32x4 sf[4];
    #pragma unroll
    for (int cb = 0; cb < 4; cb++){
      bf16x8 kf0 = *(const bf16x8*)&Ks[cb * 16 + (lane & 15)][(lane >> 4) * 8];
      bf16x8 kf1 = *(const bf16x8*)&Ks[cb * 16 + (lane & 15)][32 + (lane >> 4) * 8];
      f32x4 sacc = (f32x4){0.f, 0.f, 0.f, 0.f};
      sacc = __builtin_amdgcn_mfma_f32_16x16x32_bf16(qf0, kf0, sacc, 0, 0, 0);
      sacc = __builtin_amdgcn_mfma_f32_16x16x32_bf16(qf1, kf1, sacc, 0, 0, 0);
      sf[cb] = sacc;
    }
    #pragma unroll
    for (int r = 0; r < 4; r++){
      float mx = fmaxf(fmaxf(sf[0][r], sf[1][r]), fmaxf(sf[2][r], sf[3][r]));
      #pragma unroll
      for (int d = 1; d < 16; d <<= 1) mx = fmaxf(mx, __shfl_xor(mx, d, 64));
      float mn = fmaxf(m_r[r], mx);
      float fr = expf(m_r[r] - mn);
      m_r[r] = mn;
      float ps = 0.f;
      #pragma unroll
      for (int cb = 0; cb < 4; cb++){
        float pe = expf(sf[cb][r] - mn);
        sf[cb][r] = pe;
        ps += pe;
      }
      #pragma unroll
      for (int d = 1; d < 16; d <<= 1) ps += __shfl_xor(ps, d, 64);
      l_r[r] = l_r[r] * fr + ps;
      #pragma unroll
      for (int hb = 0; hb < 4; hb++) oa[hb][r] *= fr;
    }
    #pragma unroll
    for (int cb = 0; cb < 4; cb++)
      #pragma unroll
      for (int r = 0; r < 4; r++)
        Ps[w][(lane >> 4) * 4 + r][cb * 16 + (lane & 15)] = (__bf16)sf[cb][r];
    __syncthreads();
    bf16x8 pf0 = *(const bf16x8*)&Ps[w][lane & 15][(lane >> 4) * 8];
    bf16x8 pf1 = *(const bf16x8*)&Ps[w][lane & 15][32 + (lane >> 4) * 8];
    #pragma unroll
    for (int hb = 0; hb < 4; hb++){
      bf16x8 vf0 = *(const bf16x8*)&Vt[hb * 16 + (lane & 15)][(lane >> 4) * 8];
      bf16x8 vf1 = *(const bf16x8*)&Vt[hb * 16 + (lane & 15)][32 + (lane >> 4) * 8];
      oa[hb] = __builtin_amdgcn_mfma_f32_16x16x32_bf16(pf0, vf0, oa[hb], 0, 0, 0);
      oa[hb] = __builtin_amdgcn_mfma_f32_16x16x32_bf16(pf1, vf1, oa[hb], 0, 0, 0);
    }
    __syncthreads();
  }
  #pragma unroll
  for (int hb = 0; hb < 4; hb++)
    #pragma unroll
    for (int r = 0; r < 4; r++){
      long row = tokbase + q0 + w * 16 + (lane >> 4) * 4 + r;
      float val = oa[hb][r] / l_r[r];
      og[row * 1024 + hd0 + hb * 16 + (lane & 15)] = (__bf16)val;
    }
}

// ---------------- m97-style GEMM: global_load_lds + XOR block-swizzle (both sides)
// C[M,N] = A[M,K] @ Bt[N,K]^T, 128x128 tile, BK=64, 4 waves
// EPI: 0=store bf16, 1=gelu->bf16, 2=h=resid+gate*acc (f32), 3=store f32, 4=atomicAdd(w*acc)
// GMODE: 0=linear, 1=expert GEMM1 (src=pair>>1, dst=pair), 2=expert GEMM2 (src=pair, dst=pair>>1)
template<int EPI, int GMODE>
__global__ __launch_bounds__(256)
void gemm_k(const __bf16* __restrict__ A, int lda,
            const __bf16* __restrict__ Bt, int K, long bstride,
            const int* __restrict__ lists, const int* __restrict__ counts,
            __bf16* __restrict__ outb, int ldo,
            float* __restrict__ outf,
            const float* __restrict__ resid,
            const float* __restrict__ mods, int mod_off,
            const float* __restrict__ wpair){
  int e = blockIdx.z;
  int cnt = 1 << 30;
  const int* list = nullptr;
  if (GMODE){
    cnt = counts[e];
    if ((int)blockIdx.y * 128 >= cnt) return;
    list = lists + e * 4096;
    Bt += (long)e * bstride;
  }
  int row0 = blockIdx.y * 128;
  int n0 = blockIdx.x * 128;
  int tid = threadIdx.x;
  int lane = tid & 63, w = tid >> 6;
  int wr = (w >> 1) * 64, wc = (w & 1) * 64;

  __shared__ __bf16 As[128 * 64];
  __shared__ __bf16 Bs[128 * 64];

  f32x4 acc[4][4];
  #pragma unroll
  for (int m = 0; m < 4; m++)
    #pragma unroll
    for (int n = 0; n < 4; n++) acc[m][n] = (f32x4){0.f, 0.f, 0.f, 0.f};

  // staging: wave w covers tile rows [w*32, w*32+32); call j covers 8 rows; lane -> row w*32+j*8+(lane>>3)
  // source col-block pre-swizzled: scb = (lane&7) ^ (row&7)  (linear LDS dest, involution restored on read)
  long aoff[4]; const __bf16* bptr[4];
  #pragma unroll
  for (int j = 0; j < 4; j++){
    int r = w * 32 + j * 8 + (lane >> 3);
    int scb = (lane & 7) ^ (r & 7);
    int gr = row0 + r;
    int srcr;
    if (GMODE == 0) srcr = gr;
    else if (gr < cnt){ int pv = list[gr]; srcr = (GMODE == 1) ? (pv >> 1) : pv; }
    else { int pv = list[0]; srcr = (GMODE == 1) ? (pv >> 1) : pv; }  // harmless garbage row
    aoff[j] = (long)srcr * lda + scb * 8;
    bptr[j] = Bt + (long)(n0 + r) * K + scb * 8;
  }
  const int nk = K / 64;
  for (int kt = 0; kt < nk; ++kt){
    int k0 = kt * 64;
    #pragma unroll
    for (int j = 0; j < 4; j++){
      gload_lds16(A + aoff[j] + k0, &As[(w * 32 + j * 8) * 64]);
      gload_lds16(bptr[j] + k0,     &Bs[(w * 32 + j * 8) * 64]);
    }
    __syncthreads();
    #pragma unroll
    for (int ks = 0; ks < 2; ++ks){
      bf16x8 af[4], bfr[4];
      #pragma unroll
      for (int m = 0; m < 4; m++){
        int r = wr + m * 16 + (lane & 15);
        int blk = (ks * 4 + (lane >> 4)) ^ (r & 7);
        af[m] = *(const bf16x8*)&As[r * 64 + blk * 8];
      }
      #pragma unroll
      for (int n = 0; n < 4; n++){
        int r = wc + n * 16 + (lane & 15);
        int blk = (ks * 4 + (lane >> 4)) ^ (r & 7);
        bfr[n] = *(const bf16x8*)&Bs[r * 64 + blk * 8];
      }
      #pragma unroll
      for (int m = 0; m < 4; m++)
        #pragma unroll
        for (int n = 0; n < 4; n++)
          acc[m][n] = __builtin_amdgcn_mfma_f32_16x16x32_bf16(af[m], bfr[n], acc[m][n], 0, 0, 0);
    }
    __syncthreads();
  }
  #pragma unroll
  for (int m = 0; m < 4; m++){
    #pragma unroll
    for (int r = 0; r < 4; r++){
      int rl = wr + m * 16 + (lane >> 4) * 4 + r;
      int grow = row0 + rl;
      if (GMODE && grow >= cnt) continue;
      #pragma unroll
      for (int n = 0; n < 4; n++){
        int col = n0 + wc + n * 16 + (lane & 15);
        float v = acc[m][n][r];
        if (EPI == 0){
          outb[(long)grow * ldo + col] = (__bf16)v;
        } else if (EPI == 1){
          int dst = (GMODE == 1) ? list[grow] : grow;
          outb[(long)dst * ldo + col] = (__bf16)gelu_t(v);
        } else if (EPI == 2){
          int b = grow >> 10;
          outf[(long)grow * 1024 + col] = resid[(long)grow * 1024 + col] + mods[b * 6144 + mod_off + col] * v;
        } else if (EPI == 3){
          outf[(long)grow * 1024 + col] = v;
        } else if (EPI == 4){
          int pv = list[grow];
          atomicAdd(&outf[(long)(pv >> 1) * 1024 + col], wpair[pv] * v);
        }
      }
    }
  }
}

// ---------------- final: out = h + gate_mlp * y
__global__ __launch_bounds__(256)
void final_k(const float* __restrict__ h, const float* __restrict__ y,
             const float* __restrict__ mods, float* __restrict__ out){
  int i = blockIdx.x * 256 + threadIdx.x;
  long base = (long)i * 4;
  int row = (int)(base >> 10); int b = row >> 10; int c = (int)(base & 1023);
  float4 hv = *(const float4*)&h[base];
  float4 yv = *(const float4*)&y[base];
  const float* g = &mods[b * 6144 + 5120 + c];
  float4 o;
  o.x = hv.x + g[0] * yv.x;
  o.y = hv.y + g[1] * yv.y;
  o.z = hv.z + g[2] * yv.z;
  o.w = hv.w + g[3] * yv.w;
  *(float4*)&out[base] = o;
}

extern "C" void kernel_launch(void* const* d_in, const int* in_sizes, int n_in,
                              void* d_out, int out_size, void* d_ws, size_t ws_size,
                              hipStream_t stream){
  const float* hidden = (const float*)d_in[0];
  const float* cond   = (const float*)d_in[1];
  const float* adaW   = (const float*)d_in[2];
  const float* ln1s   = (const float*)d_in[3];
  const float* ln1b   = (const float*)d_in[4];
  const float* ln2s   = (const float*)d_in[5];
  const float* ln2b   = (const float*)d_in[6];
  const float* Wq     = (const float*)d_in[7];
  const float* Wk     = (const float*)d_in[8];
  const float* Wv     = (const float*)d_in[9];
  const float* Wo     = (const float*)d_in[10];
  const float* gatek  = (const float*)d_in[11];
  const float* We1    = (const float*)d_in[12];
  const float* We2    = (const float*)d_in[13];
  const float* Ws1    = (const float*)d_in[14];
  const float* Ws2    = (const float*)d_in[15];
  float* out = (float*)d_out;

  const size_t MB = 1024 * 1024;
  char* W = (char*)d_ws;
  size_t off = 0;
  auto take = [&](size_t b) -> void* {
    void* p = W + off;
    off += (b + 255) & ~((size_t)255);
    return p;
  };
  float*  mods   = (float*) take(4 * 6144 * sizeof(float));
  __bf16* qkvT   = (__bf16*)take(6 * MB);   // [3072][1024]
  __bf16* WoT    = (__bf16*)take(2 * MB);
  __bf16* Ws1T   = (__bf16*)take(4 * MB);
  __bf16* Ws2T   = (__bf16*)take(4 * MB);
  __bf16* We1T   = (__bf16*)take(16 * MB);
  __bf16* We2T   = (__bf16*)take(16 * MB);
  __bf16* n1     = (__bf16*)take(8 * MB);   // [4096][1024]
  __bf16* ab     = (__bf16*)take(8 * MB);   // attn out [4096][1024]  (n1+ab contiguous = EH alias)
  __bf16* qkv    = (__bf16*)take(24 * MB);  // [4096][3072]
  float*  hb     = (float*) take(16 * MB);
  __bf16* n2     = (__bf16*)take(8 * MB);
  float*  yb     = (float*) take(16 * MB);
  int*    counts = (int*)   take(256);
  int*    lists  = (int*)   take(8 * 4096 * 4);
  float*  wpair  = (float*) take(8192 * 4);
  __bf16* EH = n1;   // [8192][1024] = 16 MB, aliases n1+ab (both dead by expert GEMM1)
  __bf16* SH = qkv;  // [4096][2048] = 16 MB, aliases qkv (dead after attention)

  dim3 blk(256);

  hipMemsetAsync(counts, 0, 32, stream);
  hipMemsetAsync(mods, 0, 4 * 6144 * sizeof(float), stream);

  // weight transposes (fp32 -> bf16 [N][K]); QKV packed into one [3072][1024]
  transpose_cvt<<<dim3(32, 32, 1), blk, 0, stream>>>(Wq,  qkvT,              1024, 1024);
  transpose_cvt<<<dim3(32, 32, 1), blk, 0, stream>>>(Wk,  qkvT + 1024*1024,  1024, 1024);
  transpose_cvt<<<dim3(32, 32, 1), blk, 0, stream>>>(Wv,  qkvT + 2048*1024,  1024, 1024);
  transpose_cvt<<<dim3(32, 32, 1), blk, 0, stream>>>(Wo,  WoT,  1024, 1024);
  transpose_cvt<<<dim3(64, 32, 1), blk, 0, stream>>>(Ws1, Ws1T, 1024, 2048);
  transpose_cvt<<<dim3(32, 64, 1), blk, 0, stream>>>(Ws2, Ws2T, 2048, 1024);
  transpose_cvt<<<dim3(32, 32, 8), blk, 0, stream>>>(We1, We1T, 1024, 1024);
  transpose_cvt<<<dim3(32, 32, 8), blk, 0, stream>>>(We2, We2T, 1024, 1024);

  adaln_k<<<dim3(6, 4, 4), blk, 0, stream>>>(cond, adaW, mods);

  // LN1 + modulate (shift_msa@0, scale_msa@1024)
  ln_mod<<<4096, blk, 0, stream>>>(hidden, ln1s, ln1b, mods, 0, 1024, n1);

  // fused QKV projection: [4096][3072]
  gemm_k<0, 0><<<dim3(24, 32, 1), blk, 0, stream>>>(n1, 1024, qkvT, 1024, 0, nullptr, nullptr, qkv, 3072, nullptr, nullptr, nullptr, 0, nullptr);

  attn_k<<<dim3(16, 64, 1), blk, 0, stream>>>(qkv, ab);

  // h = hidden + gate_msa (mods@2048) * (attn @ Wo)
  gemm_k<2, 0><<<dim3(8, 32, 1), blk, 0, stream>>>(ab, 1024, WoT, 1024, 0, nullptr, nullptr, nullptr, 0, hb, hidden, mods, 2048, nullptr);

  // LN2 + modulate (shift_mlp@3072, scale_mlp@4096)
  ln_mod<<<4096, blk, 0, stream>>>(hb, ln2s, ln2b, mods, 3072, 4096, n2);

  // MoE gate (fp32 recompute of normed2 from h)
  gate_k<<<1024, blk, 0, stream>>>(hb, ln2s, ln2b, mods, gatek, counts, lists, wpair);

  // shared experts: SH = gelu(n2 @ Ws1); y = SH @ Ws2
  gemm_k<1, 0><<<dim3(16, 32, 1), blk, 0, stream>>>(n2, 1024, Ws1T, 1024, 0, nullptr, nullptr, SH, 2048, nullptr, nullptr, nullptr, 0, nullptr);
  gemm_k<3, 0><<<dim3(8, 32, 1), blk, 0, stream>>>(SH, 2048, Ws2T, 2048, 0, nullptr, nullptr, nullptr, 0, yb, nullptr, nullptr, 0, nullptr);

  // routed experts (top-2 only): EH = gelu(gather(n2) @ We1[e]); y += w * (EH @ We2[e])
  gemm_k<1, 1><<<dim3(8, 32, 8), blk, 0, stream>>>(n2, 1024, We1T, 1024, 1048576, lists, counts, EH, 1024, nullptr, nullptr, nullptr, 0, nullptr);
  gemm_k<4, 2><<<dim3(8, 32, 8), blk, 0, stream>>>(EH, 1024, We2T, 1024, 1048576, lists, counts, nullptr, 0, yb, nullptr, nullptr, 0, wpair);

  // out = h + gate_mlp (mods@5120) * y
  final_k<<<4096, blk, 0, stream>>>(hb, yb, mods, out);

  (void)in_sizes; (void)n_in; (void)out_size; (void)ws_size;
}

// Round 3
// 582.284 us; speedup vs baseline: 1.4103x; 1.1465x over previous
//
#include <hip/hip_runtime.h>

typedef __bf16 bf16x8 __attribute__((ext_vector_type(8)));
typedef __bf16 bf16x4 __attribute__((ext_vector_type(4)));
typedef float  f32x4  __attribute__((ext_vector_type(4)));

__device__ inline float wred_sum(float v){
  #pragma unroll
  for (int d = 1; d < 64; d <<= 1) v += __shfl_xor(v, d, 64);
  return v;
}

__device__ inline float gelu_t(float x){
  const float c0 = 0.7978845608028654f;
  float t = tanhf(c0 * (x + 0.044715f * x * x * x));
  return 0.5f * x * (1.0f + t);
}

__device__ __forceinline__ void gload_lds16(const __bf16* g, __bf16* l){
  __builtin_amdgcn_global_load_lds((const __attribute__((address_space(1))) void*)g,
                                   (__attribute__((address_space(3))) void*)l, 16, 0, 0);
}

// ---------------- transpose + fp32->bf16 convert: in[R][C] f32 -> out[C][R] bf16
__global__ __launch_bounds__(256)
void transpose_cvt(const float* __restrict__ in, __bf16* __restrict__ out, int R, int C){
  long mo = (long)blockIdx.z * R * C;
  in += mo; out += mo;
  __shared__ float t[32][33];
  int r0 = blockIdx.y * 32, c0 = blockIdx.x * 32;
  int tid = threadIdx.x;
  int tr = tid >> 3, tc = (tid & 7) * 4;
  float4 vv = *(const float4*)&in[(long)(r0 + tr) * C + c0 + tc];
  t[tr][tc + 0] = vv.x; t[tr][tc + 1] = vv.y; t[tr][tc + 2] = vv.z; t[tr][tc + 3] = vv.w;
  __syncthreads();
  int oc = tid >> 3, orr = (tid & 7) * 4;
  bf16x4 o4;
  #pragma unroll
  for (int i = 0; i < 4; i++) o4[i] = (__bf16)t[orr + i][oc];
  *(bf16x4*)&out[(long)(c0 + oc) * R + r0 + orr] = o4;
}

// ---------------- adaLN: mods[b][0:6144] += partial over h2-chunk (split-K, fp32 atomics)
__global__ __launch_bounds__(256)
void adaln_k(const float* __restrict__ cond, const float* __restrict__ W, float* __restrict__ mods){
  int b = blockIdx.y, z = blockIdx.z;
  int col = (blockIdx.x * 256 + threadIdx.x) * 4;
  __shared__ float sc[256];
  int h2 = z * 256 + threadIdx.x;
  float x = cond[b * 1024 + h2];
  sc[threadIdx.x] = x / (1.f + expf(-x));
  __syncthreads();
  float a0 = 0.f, a1 = 0.f, a2 = 0.f, a3 = 0.f;
  #pragma unroll 4
  for (int i = 0; i < 256; i++){
    float s = sc[i];
    float4 wv = *(const float4*)&W[(long)(z * 256 + i) * 6144 + col];
    a0 += s * wv.x; a1 += s * wv.y; a2 += s * wv.z; a3 += s * wv.w;
  }
  atomicAdd(&mods[b * 6144 + col + 0], a0);
  atomicAdd(&mods[b * 6144 + col + 1], a1);
  atomicAdd(&mods[b * 6144 + col + 2], a2);
  atomicAdd(&mods[b * 6144 + col + 3], a3);
}

// ---------------- LayerNorm + modulate -> bf16
__global__ __launch_bounds__(256)
void ln_mod(const float* __restrict__ x, const float* __restrict__ sc, const float* __restrict__ bi,
            const float* __restrict__ mods, int shift_off, int scale_off, __bf16* __restrict__ out){
  int row = blockIdx.x, tid = threadIdx.x, b = row >> 10;
  float4 xv = *(const float4*)&x[(long)row * 1024 + tid * 4];
  float s  = xv.x + xv.y + xv.z + xv.w;
  float s2 = xv.x * xv.x + xv.y * xv.y + xv.z * xv.z + xv.w * xv.w;
  s = wred_sum(s); s2 = wred_sum(s2);
  __shared__ float ssum[4], ssum2[4];
  int w = tid >> 6;
  if ((tid & 63) == 0){ ssum[w] = s; ssum2[w] = s2; }
  __syncthreads();
  s = ssum[0] + ssum[1] + ssum[2] + ssum[3];
  s2 = ssum2[0] + ssum2[1] + ssum2[2] + ssum2[3];
  float mean = s * (1.f / 1024.f);
  float var  = s2 * (1.f / 1024.f) - mean * mean;
  float inv  = rsqrtf(var + 1e-6f);
  const float xa[4] = {xv.x, xv.y, xv.z, xv.w};
  #pragma unroll
  for (int i = 0; i < 4; i++){
    int c = tid * 4 + i;
    float nv = (xa[i] - mean) * inv * sc[c] + bi[c];
    nv = nv * (1.f + mods[b * 6144 + scale_off + c]) + mods[b * 6144 + shift_off + c];
    out[(long)row * 1024 + c] = (__bf16)nv;
  }
}

// ---------------- gate: 4 tokens/block, gw in LDS, fp32 LN2 recompute, top2 -> eidx/wpair (NO atomics)
__global__ __launch_bounds__(256)
void gate_k(const float* __restrict__ h, const float* __restrict__ ln2s, const float* __restrict__ ln2b,
            const float* __restrict__ mods, const float* __restrict__ gw,
            int* __restrict__ eidx, float* __restrict__ wpair){
  __shared__ float gws[8192];
  int tid = threadIdx.x;
  #pragma unroll
  for (int i = 0; i < 8; i++){
    int idx = tid + i * 256;
    *(float4*)&gws[idx * 4] = *(const float4*)&gw[idx * 4];
  }
  __syncthreads();
  int wv = tid >> 6, lane = tid & 63;
  int tok = blockIdx.x * 4 + wv;
  int b = tok >> 10;
  float4 xv[4]; float s = 0.f, s2 = 0.f;
  #pragma unroll
  for (int ch = 0; ch < 4; ch++){
    float4 v = *(const float4*)&h[(long)tok * 1024 + ch * 256 + lane * 4];
    xv[ch] = v;
    s  += v.x + v.y + v.z + v.w;
    s2 += v.x * v.x + v.y * v.y + v.z * v.z + v.w * v.w;
  }
  s = wred_sum(s); s2 = wred_sum(s2);
  float mean = s * (1.f / 1024.f);
  float var  = s2 * (1.f / 1024.f) - mean * mean;
  float inv  = rsqrtf(var + 1e-6f);
  float lg[8];
  #pragma unroll
  for (int e = 0; e < 8; e++) lg[e] = 0.f;
  #pragma unroll
  for (int ch = 0; ch < 4; ch++){
    int c = ch * 256 + lane * 4;
    float4 s4  = *(const float4*)&ln2s[c];
    float4 b4  = *(const float4*)&ln2b[c];
    float4 sc4 = *(const float4*)&mods[b * 6144 + 4096 + c];
    float4 sh4 = *(const float4*)&mods[b * 6144 + 3072 + c];
    float n0 = ((xv[ch].x - mean) * inv * s4.x + b4.x) * (1.f + sc4.x) + sh4.x;
    float n1 = ((xv[ch].y - mean) * inv * s4.y + b4.y) * (1.f + sc4.y) + sh4.y;
    float n2 = ((xv[ch].z - mean) * inv * s4.z + b4.z) * (1.f + sc4.z) + sh4.z;
    float n3 = ((xv[ch].w - mean) * inv * s4.w + b4.w) * (1.f + sc4.w) + sh4.w;
    #pragma unroll
    for (int e = 0; e < 8; e++){
      float4 g4 = *(const float4*)&gws[e * 1024 + c];
      lg[e] += n0 * g4.x + n1 * g4.y + n2 * g4.z + n3 * g4.w;
    }
  }
  #pragma unroll
  for (int e = 0; e < 8; e++) lg[e] = wred_sum(lg[e]);
  if (lane == 0){
    float mx = lg[0];
    #pragma unroll
    for (int e = 1; e < 8; e++) mx = fmaxf(mx, lg[e]);
    float p[8], ss = 0.f;
    #pragma unroll
    for (int e = 0; e < 8; e++){ p[e] = expf(lg[e] - mx); ss += p[e]; }
    #pragma unroll
    for (int e = 0; e < 8; e++) p[e] /= ss;
    int i0 = 0; float b0 = p[0];
    #pragma unroll
    for (int e = 1; e < 8; e++) if (p[e] > b0){ b0 = p[e]; i0 = e; }
    int i1 = -1; float b1 = -1.f;
    #pragma unroll
    for (int e = 0; e < 8; e++) if (e != i0 && p[e] > b1){ b1 = p[e]; i1 = e; }
    float dn = b0 + b1 + 1e-20f;
    eidx[tok * 2]     = i0; wpair[tok * 2]     = b0 / dn;
    eidx[tok * 2 + 1] = i1; wpair[tok * 2 + 1] = b1 / dn;
  }
}

// ---------------- build routing lists: 1 block per expert, ordered ballot compaction
__global__ __launch_bounds__(256)
void build_k(const int* __restrict__ eidx, int* __restrict__ counts, int* __restrict__ lists){
  int e = blockIdx.x;
  int tid = threadIdx.x, wv = tid >> 6, lane = tid & 63;
  __shared__ int base;
  __shared__ int woff[4];
  if (tid == 0) base = 0;
  __syncthreads();
  for (int it = 0; it < 32; ++it){
    int i = it * 256 + tid;
    bool m = (eidx[i] == e);
    unsigned long long bal = __ballot(m);
    int prefix = __popcll(bal & ((1ull << lane) - 1ull));
    if (lane == 0) woff[wv] = __popcll(bal);
    __syncthreads();
    int off = base;
    #pragma unroll
    for (int k = 0; k < 4; k++) if (k < wv) off += woff[k];
    if (m) lists[e * 4096 + off + prefix] = i;
    __syncthreads();
    if (tid == 0) base += woff[0] + woff[1] + woff[2] + woff[3];
    __syncthreads();
  }
  if (tid == 0) counts[e] = base;
}

// ---------------- flash attention over fused qkv [4096][3072]
__global__ __launch_bounds__(256)
void attn_k(const __bf16* __restrict__ qkv, __bf16* __restrict__ og){
  int bh = blockIdx.y; int bb = bh >> 4, hn = bh & 15;
  int q0 = blockIdx.x * 64;
  long tokbase = (long)bb * 1024;
  int hd0 = hn * 64;
  int tid = threadIdx.x; int w = tid >> 6; int lane = tid & 63;

  __shared__ __bf16 Ks[64][72];
  __shared__ __bf16 Vt[64][72];
  __shared__ __bf16 Ps[4][16][72];

  long qrow = tokbase + q0 + w * 16 + (lane & 15);
  bf16x8 qf0 = *(const bf16x8*)&qkv[qrow * 3072 + hd0 + (lane >> 4) * 8];
  bf16x8 qf1 = *(const bf16x8*)&qkv[qrow * 3072 + hd0 + 32 + (lane >> 4) * 8];
  #pragma unroll
  for (int i = 0; i < 8; i++){  // fold 1/sqrt(64) into q (exact in bf16)
    qf0[i] = (__bf16)((float)qf0[i] * 0.125f);
    qf1[i] = (__bf16)((float)qf1[i] * 0.125f);
  }

  float m_r[4], l_r[4];
  f32x4 oa[4];
  #pragma unroll
  for (int r = 0; r < 4; r++){ m_r[r] = -1e30f; l_r[r] = 0.f; }
  #pragma unroll
  for (int hb = 0; hb < 4; hb++) oa[hb] = (f32x4){0.f, 0.f, 0.f, 0.f};

  int dcol = tid & 63, rblk = tid >> 6;
  for (int t = 0; t < 16; t++){
    long kvbase = tokbase + t * 64;
    #pragma unroll
    for (int p = 0; p < 2; p++){
      int r = (tid >> 3) + p * 32;
      int c = (tid & 7) * 8;
      *(bf16x8*)&Ks[r][c] = *(const bf16x8*)&qkv[(kvbase + r) * 3072 + 1024 + hd0 + c];
    }
    // V: each lane loads a column (coalesced across lanes), writes contiguous Vt row chunk
    bf16x8 col0, col1;
    #pragma unroll
    for (int i = 0; i < 8; i++)
      col0[i] = qkv[(kvbase + rblk * 16 + i) * 3072 + 2048 + hd0 + dcol];
    #pragma unroll
    for (int i = 0; i < 8; i++)
      col1[i] = qkv[(kvbase + rblk * 16 + 8 + i) * 3072 + 2048 + hd0 + dcol];
    *(bf16x8*)&Vt[dcol][rblk * 16]     = col0;
    *(bf16x8*)&Vt[dcol][rblk * 16 + 8] = col1;
    __syncthreads();
    f32x4 sf[4];
    #pragma unroll
    for (int cb = 0; cb < 4; cb++){
      bf16x8 kf0 = *(const bf16x8*)&Ks[cb * 16 + (lane & 15)][(lane >> 4) * 8];
      bf16x8 kf1 = *(const bf16x8*)&Ks[cb * 16 + (lane & 15)][32 + (lane >> 4) * 8];
      f32x4 sacc = (f32x4){0.f, 0.f, 0.f, 0.f};
      sacc = __builtin_amdgcn_mfma_f32_16x16x32_bf16(qf0, kf0, sacc, 0, 0, 0);
      sacc = __builtin_amdgcn_mfma_f32_16x16x32_bf16(qf1, kf1, sacc, 0, 0, 0);
      sf[cb] = sacc;
    }
    #pragma unroll
    for (int r = 0; r < 4; r++){
      float mx = fmaxf(fmaxf(sf[0][r], sf[1][r]), fmaxf(sf[2][r], sf[3][r]));
      #pragma unroll
      for (int d = 1; d < 16; d <<= 1) mx = fmaxf(mx, __shfl_xor(mx, d, 64));
      float mn = fmaxf(m_r[r], mx);
      float fr = expf(m_r[r] - mn);
      m_r[r] = mn;
      float ps = 0.f;
      #pragma unroll
      for (int cb = 0; cb < 4; cb++){
        float pe = expf(sf[cb][r] - mn);
        sf[cb][r] = pe;
        ps += pe;
      }
      #pragma unroll
      for (int d = 1; d < 16; d <<= 1) ps += __shfl_xor(ps, d, 64);
      l_r[r] = l_r[r] * fr + ps;
      #pragma unroll
      for (int hb = 0; hb < 4; hb++) oa[hb][r] *= fr;
    }
    #pragma unroll
    for (int cb = 0; cb < 4; cb++)
      #pragma unroll
      for (int r = 0; r < 4; r++)
        Ps[w][(lane >> 4) * 4 + r][cb * 16 + (lane & 15)] = (__bf16)sf[cb][r];
    __syncthreads();
    bf16x8 pf0 = *(const bf16x8*)&Ps[w][lane & 15][(lane >> 4) * 8];
    bf16x8 pf1 = *(const bf16x8*)&Ps[w][lane & 15][32 + (lane >> 4) * 8];
    #pragma unroll
    for (int hb = 0; hb < 4; hb++){
      bf16x8 vf0 = *(const bf16x8*)&Vt[hb * 16 + (lane & 15)][(lane >> 4) * 8];
      bf16x8 vf1 = *(const bf16x8*)&Vt[hb * 16 + (lane & 15)][32 + (lane >> 4) * 8];
      oa[hb] = __builtin_amdgcn_mfma_f32_16x16x32_bf16(pf0, vf0, oa[hb], 0, 0, 0);
      oa[hb] = __builtin_amdgcn_mfma_f32_16x16x32_bf16(pf1, vf1, oa[hb], 0, 0, 0);
    }
    __syncthreads();
  }
  #pragma unroll
  for (int hb = 0; hb < 4; hb++)
    #pragma unroll
    for (int r = 0; r < 4; r++){
      long row = tokbase + q0 + w * 16 + (lane >> 4) * 4 + r;
      float val = oa[hb][r] / l_r[r];
      og[row * 1024 + hd0 + hb * 16 + (lane & 15)] = (__bf16)val;
    }
}

// ---------------- m97-style GEMM: global_load_lds + XOR block-swizzle (both sides)
// C[M,N] = A[M,K] @ Bt[N,K]^T, 128x128 tile, BK=64, 4 waves
// EPI: 0=store bf16, 1=gelu->bf16, 2=h=resid+gate*acc (f32), 3=store f32, 4=atomicAdd(w*acc)
// GMODE: 0=linear, 1=expert GEMM1 (src=pair>>1, dst=pair), 2=expert GEMM2 (src=pair, dst=pair>>1)
template<int EPI, int GMODE>
__global__ __launch_bounds__(256)
void gemm_k(const __bf16* __restrict__ A, int lda,
            const __bf16* __restrict__ Bt, int K, long bstride,
            const int* __restrict__ lists, const int* __restrict__ counts,
            __bf16* __restrict__ outb, int ldo,
            float* __restrict__ outf,
            const float* __restrict__ resid,
            const float* __restrict__ mods, int mod_off,
            const float* __restrict__ wpair){
  int e = blockIdx.z;
  int cnt = 1 << 30;
  const int* list = nullptr;
  if (GMODE){
    cnt = counts[e];
    if ((int)blockIdx.y * 128 >= cnt) return;
    list = lists + e * 4096;
    Bt += (long)e * bstride;
  }
  int row0 = blockIdx.y * 128;
  int n0 = blockIdx.x * 128;
  int tid = threadIdx.x;
  int lane = tid & 63, w = tid >> 6;
  int wr = (w >> 1) * 64, wc = (w & 1) * 64;

  __shared__ __bf16 As[128 * 64];
  __shared__ __bf16 Bs[128 * 64];

  f32x4 acc[4][4];
  #pragma unroll
  for (int m = 0; m < 4; m++)
    #pragma unroll
    for (int n = 0; n < 4; n++) acc[m][n] = (f32x4){0.f, 0.f, 0.f, 0.f};

  long aoff[4]; const __bf16* bptr[4];
  #pragma unroll
  for (int j = 0; j < 4; j++){
    int r = w * 32 + j * 8 + (lane >> 3);
    int scb = (lane & 7) ^ (r & 7);
    int gr = row0 + r;
    int srcr;
    if (GMODE == 0) srcr = gr;
    else if (gr < cnt){ int pv = list[gr]; srcr = (GMODE == 1) ? (pv >> 1) : pv; }
    else { int pv = list[0]; srcr = (GMODE == 1) ? (pv >> 1) : pv; }  // harmless garbage row
    aoff[j] = (long)srcr * lda + scb * 8;
    bptr[j] = Bt + (long)(n0 + r) * K + scb * 8;
  }
  const int nk = K / 64;
  for (int kt = 0; kt < nk; ++kt){
    int k0 = kt * 64;
    #pragma unroll
    for (int j = 0; j < 4; j++){
      gload_lds16(A + aoff[j] + k0, &As[(w * 32 + j * 8) * 64]);
      gload_lds16(bptr[j] + k0,     &Bs[(w * 32 + j * 8) * 64]);
    }
    __syncthreads();
    #pragma unroll
    for (int ks = 0; ks < 2; ++ks){
      bf16x8 af[4], bfr[4];
      #pragma unroll
      for (int m = 0; m < 4; m++){
        int r = wr + m * 16 + (lane & 15);
        int blk = (ks * 4 + (lane >> 4)) ^ (r & 7);
        af[m] = *(const bf16x8*)&As[r * 64 + blk * 8];
      }
      #pragma unroll
      for (int n = 0; n < 4; n++){
        int r = wc + n * 16 + (lane & 15);
        int blk = (ks * 4 + (lane >> 4)) ^ (r & 7);
        bfr[n] = *(const bf16x8*)&Bs[r * 64 + blk * 8];
      }
      #pragma unroll
      for (int m = 0; m < 4; m++)
        #pragma unroll
        for (int n = 0; n < 4; n++)
          acc[m][n] = __builtin_amdgcn_mfma_f32_16x16x32_bf16(af[m], bfr[n], acc[m][n], 0, 0, 0);
    }
    __syncthreads();
  }
  #pragma unroll
  for (int m = 0; m < 4; m++){
    #pragma unroll
    for (int r = 0; r < 4; r++){
      int rl = wr + m * 16 + (lane >> 4) * 4 + r;
      int grow = row0 + rl;
      if (GMODE && grow >= cnt) continue;
      #pragma unroll
      for (int n = 0; n < 4; n++){
        int col = n0 + wc + n * 16 + (lane & 15);
        float v = acc[m][n][r];
        if (EPI == 0){
          outb[(long)grow * ldo + col] = (__bf16)v;
        } else if (EPI == 1){
          int dst = (GMODE == 1) ? list[grow] : grow;
          outb[(long)dst * ldo + col] = (__bf16)gelu_t(v);
        } else if (EPI == 2){
          int b = grow >> 10;
          outf[(long)grow * 1024 + col] = resid[(long)grow * 1024 + col] + mods[b * 6144 + mod_off + col] * v;
        } else if (EPI == 3){
          outf[(long)grow * 1024 + col] = v;
        } else if (EPI == 4){
          int pv = list[grow];
          atomicAdd(&outf[(long)(pv >> 1) * 1024 + col], wpair[pv] * v);
        }
      }
    }
  }
}

// ---------------- final: out = h + gate_mlp * y
__global__ __launch_bounds__(256)
void final_k(const float* __restrict__ h, const float* __restrict__ y,
             const float* __restrict__ mods, float* __restrict__ out){
  int i = blockIdx.x * 256 + threadIdx.x;
  long base = (long)i * 4;
  int row = (int)(base >> 10); int b = row >> 10; int c = (int)(base & 1023);
  float4 hv = *(const float4*)&h[base];
  float4 yv = *(const float4*)&y[base];
  const float* g = &mods[b * 6144 + 5120 + c];
  float4 o;
  o.x = hv.x + g[0] * yv.x;
  o.y = hv.y + g[1] * yv.y;
  o.z = hv.z + g[2] * yv.z;
  o.w = hv.w + g[3] * yv.w;
  *(float4*)&out[base] = o;
}

extern "C" void kernel_launch(void* const* d_in, const int* in_sizes, int n_in,
                              void* d_out, int out_size, void* d_ws, size_t ws_size,
                              hipStream_t stream){
  const float* hidden = (const float*)d_in[0];
  const float* cond   = (const float*)d_in[1];
  const float* adaW   = (const float*)d_in[2];
  const float* ln1s   = (const float*)d_in[3];
  const float* ln1b   = (const float*)d_in[4];
  const float* ln2s   = (const float*)d_in[5];
  const float* ln2b   = (const float*)d_in[6];
  const float* Wq     = (const float*)d_in[7];
  const float* Wk     = (const float*)d_in[8];
  const float* Wv     = (const float*)d_in[9];
  const float* Wo     = (const float*)d_in[10];
  const float* gatek  = (const float*)d_in[11];
  const float* We1    = (const float*)d_in[12];
  const float* We2    = (const float*)d_in[13];
  const float* Ws1    = (const float*)d_in[14];
  const float* Ws2    = (const float*)d_in[15];
  float* out = (float*)d_out;

  const size_t MB = 1024 * 1024;
  char* W = (char*)d_ws;
  size_t off = 0;
  auto take = [&](size_t b) -> void* {
    void* p = W + off;
    off += (b + 255) & ~((size_t)255);
    return p;
  };
  float*  mods   = (float*) take(4 * 6144 * sizeof(float));
  __bf16* qkvT   = (__bf16*)take(6 * MB);   // [3072][1024]
  __bf16* WoT    = (__bf16*)take(2 * MB);
  __bf16* Ws1T   = (__bf16*)take(4 * MB);
  __bf16* Ws2T   = (__bf16*)take(4 * MB);
  __bf16* We1T   = (__bf16*)take(16 * MB);
  __bf16* We2T   = (__bf16*)take(16 * MB);
  __bf16* n1     = (__bf16*)take(8 * MB);   // [4096][1024]
  __bf16* ab     = (__bf16*)take(8 * MB);   // attn out [4096][1024]  (n1+ab contiguous = EH alias)
  __bf16* qkv    = (__bf16*)take(24 * MB);  // [4096][3072]
  float*  hb     = (float*) take(16 * MB);
  __bf16* n2     = (__bf16*)take(8 * MB);
  float*  yb     = (float*) take(16 * MB);
  int*    counts = (int*)   take(256);
  int*    lists  = (int*)   take(8 * 4096 * 4);
  float*  wpair  = (float*) take(8192 * 4);
  int*    eidx   = (int*)   take(8192 * 4);
  __bf16* EH = n1;   // [8192][1024] = 16 MB, aliases n1+ab (both dead by expert GEMM1)
  __bf16* SH = qkv;  // [4096][2048] = 16 MB, aliases qkv (dead after attention)

  dim3 blk(256);

  hipMemsetAsync(mods, 0, 4 * 6144 * sizeof(float), stream);

  // weight transposes (fp32 -> bf16 [N][K]); QKV packed into one [3072][1024]
  transpose_cvt<<<dim3(32, 32, 1), blk, 0, stream>>>(Wq,  qkvT,              1024, 1024);
  transpose_cvt<<<dim3(32, 32, 1), blk, 0, stream>>>(Wk,  qkvT + 1024*1024,  1024, 1024);
  transpose_cvt<<<dim3(32, 32, 1), blk, 0, stream>>>(Wv,  qkvT + 2048*1024,  1024, 1024);
  transpose_cvt<<<dim3(32, 32, 1), blk, 0, stream>>>(Wo,  WoT,  1024, 1024);
  transpose_cvt<<<dim3(64, 32, 1), blk, 0, stream>>>(Ws1, Ws1T, 1024, 2048);
  transpose_cvt<<<dim3(32, 64, 1), blk, 0, stream>>>(Ws2, Ws2T, 2048, 1024);
  transpose_cvt<<<dim3(32, 32, 8), blk, 0, stream>>>(We1, We1T, 1024, 1024);
  transpose_cvt<<<dim3(32, 32, 8), blk, 0, stream>>>(We2, We2T, 1024, 1024);

  adaln_k<<<dim3(6, 4, 4), blk, 0, stream>>>(cond, adaW, mods);

  // LN1 + modulate (shift_msa@0, scale_msa@1024)
  ln_mod<<<4096, blk, 0, stream>>>(hidden, ln1s, ln1b, mods, 0, 1024, n1);

  // fused QKV projection: [4096][3072]
  gemm_k<0, 0><<<dim3(24, 32, 1), blk, 0, stream>>>(n1, 1024, qkvT, 1024, 0, nullptr, nullptr, qkv, 3072, nullptr, nullptr, nullptr, 0, nullptr);

  attn_k<<<dim3(16, 64, 1), blk, 0, stream>>>(qkv, ab);

  // h = hidden + gate_msa (mods@2048) * (attn @ Wo)
  gemm_k<2, 0><<<dim3(8, 32, 1), blk, 0, stream>>>(ab, 1024, WoT, 1024, 0, nullptr, nullptr, nullptr, 0, hb, hidden, mods, 2048, nullptr);

  // LN2 + modulate (shift_mlp@3072, scale_mlp@4096)
  ln_mod<<<4096, blk, 0, stream>>>(hb, ln2s, ln2b, mods, 3072, 4096, n2);

  // MoE gate (fp32 recompute of normed2 from h) + ordered list build
  gate_k<<<1024, blk, 0, stream>>>(hb, ln2s, ln2b, mods, gatek, eidx, wpair);
  build_k<<<8, blk, 0, stream>>>(eidx, counts, lists);

  // shared experts: SH = gelu(n2 @ Ws1); y = SH @ Ws2
  gemm_k<1, 0><<<dim3(16, 32, 1), blk, 0, stream>>>(n2, 1024, Ws1T, 1024, 0, nullptr, nullptr, SH, 2048, nullptr, nullptr, nullptr, 0, nullptr);
  gemm_k<3, 0><<<dim3(8, 32, 1), blk, 0, stream>>>(SH, 2048, Ws2T, 2048, 0, nullptr, nullptr, nullptr, 0, yb, nullptr, nullptr, 0, nullptr);

  // routed experts (top-2 only): EH = gelu(gather(n2) @ We1[e]); y += w * (EH @ We2[e])
  gemm_k<1, 1><<<dim3(8, 32, 8), blk, 0, stream>>>(n2, 1024, We1T, 1024, 1048576, lists, counts, EH, 1024, nullptr, nullptr, nullptr, 0, nullptr);
  gemm_k<4, 2><<<dim3(8, 32, 8), blk, 0, stream>>>(EH, 1024, We2T, 1024, 1048576, lists, counts, nullptr, 0, yb, nullptr, nullptr, 0, wpair);

  // out = h + gate_mlp (mods@5120) * y
  final_k<<<4096, blk, 0, stream>>>(hb, yb, mods, out);

  (void)in_sizes; (void)n_in; (void)out_size; (void)ws_size;
}

// Round 4
// 561.677 us; speedup vs baseline: 1.4621x; 1.0367x over previous
//
#include <hip/hip_runtime.h>

typedef __bf16 bf16x8 __attribute__((ext_vector_type(8)));
typedef __bf16 bf16x4 __attribute__((ext_vector_type(4)));
typedef float  f32x4  __attribute__((ext_vector_type(4)));

__device__ inline float wred_sum(float v){
  #pragma unroll
  for (int d = 1; d < 64; d <<= 1) v += __shfl_xor(v, d, 64);
  return v;
}

__device__ inline float gelu_t(float x){
  const float c0 = 0.7978845608028654f;
  float t = tanhf(c0 * (x + 0.044715f * x * x * x));
  return 0.5f * x * (1.0f + t);
}

__device__ __forceinline__ void gload_lds16(const __bf16* g, __bf16* l){
  __builtin_amdgcn_global_load_lds((const __attribute__((address_space(1))) void*)g,
                                   (__attribute__((address_space(3))) void*)l, 16, 0, 0);
}

// ---------------- transpose + fp32->bf16 convert: in[R][C] f32 -> out[C][R] bf16
__global__ __launch_bounds__(256)
void transpose_cvt(const float* __restrict__ in, __bf16* __restrict__ out, int R, int C){
  long mo = (long)blockIdx.z * R * C;
  in += mo; out += mo;
  __shared__ float t[32][33];
  int r0 = blockIdx.y * 32, c0 = blockIdx.x * 32;
  int tid = threadIdx.x;
  int tr = tid >> 3, tc = (tid & 7) * 4;
  float4 vv = *(const float4*)&in[(long)(r0 + tr) * C + c0 + tc];
  t[tr][tc + 0] = vv.x; t[tr][tc + 1] = vv.y; t[tr][tc + 2] = vv.z; t[tr][tc + 3] = vv.w;
  __syncthreads();
  int oc = tid >> 3, orr = (tid & 7) * 4;
  bf16x4 o4;
  #pragma unroll
  for (int i = 0; i < 4; i++) o4[i] = (__bf16)t[orr + i][oc];
  *(bf16x4*)&out[(long)(c0 + oc) * R + r0 + orr] = o4;
}

// ---------------- adaLN: mods[b][0:6144] += partial over h2-chunk (split-K, fp32 atomics)
__global__ __launch_bounds__(256)
void adaln_k(const float* __restrict__ cond, const float* __restrict__ W, float* __restrict__ mods){
  int b = blockIdx.y, z = blockIdx.z;
  int col = (blockIdx.x * 256 + threadIdx.x) * 4;
  __shared__ float sc[256];
  int h2 = z * 256 + threadIdx.x;
  float x = cond[b * 1024 + h2];
  sc[threadIdx.x] = x / (1.f + expf(-x));
  __syncthreads();
  float a0 = 0.f, a1 = 0.f, a2 = 0.f, a3 = 0.f;
  #pragma unroll 4
  for (int i = 0; i < 256; i++){
    float s = sc[i];
    float4 wv = *(const float4*)&W[(long)(z * 256 + i) * 6144 + col];
    a0 += s * wv.x; a1 += s * wv.y; a2 += s * wv.z; a3 += s * wv.w;
  }
  atomicAdd(&mods[b * 6144 + col + 0], a0);
  atomicAdd(&mods[b * 6144 + col + 1], a1);
  atomicAdd(&mods[b * 6144 + col + 2], a2);
  atomicAdd(&mods[b * 6144 + col + 3], a3);
}

// ---------------- LayerNorm + modulate -> bf16
__global__ __launch_bounds__(256)
void ln_mod(const float* __restrict__ x, const float* __restrict__ sc, const float* __restrict__ bi,
            const float* __restrict__ mods, int shift_off, int scale_off, __bf16* __restrict__ out){
  int row = blockIdx.x, tid = threadIdx.x, b = row >> 10;
  float4 xv = *(const float4*)&x[(long)row * 1024 + tid * 4];
  float s  = xv.x + xv.y + xv.z + xv.w;
  float s2 = xv.x * xv.x + xv.y * xv.y + xv.z * xv.z + xv.w * xv.w;
  s = wred_sum(s); s2 = wred_sum(s2);
  __shared__ float ssum[4], ssum2[4];
  int w = tid >> 6;
  if ((tid & 63) == 0){ ssum[w] = s; ssum2[w] = s2; }
  __syncthreads();
  s = ssum[0] + ssum[1] + ssum[2] + ssum[3];
  s2 = ssum2[0] + ssum2[1] + ssum2[2] + ssum2[3];
  float mean = s * (1.f / 1024.f);
  float var  = s2 * (1.f / 1024.f) - mean * mean;
  float inv  = rsqrtf(var + 1e-6f);
  const float xa[4] = {xv.x, xv.y, xv.z, xv.w};
  #pragma unroll
  for (int i = 0; i < 4; i++){
    int c = tid * 4 + i;
    float nv = (xa[i] - mean) * inv * sc[c] + bi[c];
    nv = nv * (1.f + mods[b * 6144 + scale_off + c]) + mods[b * 6144 + shift_off + c];
    out[(long)row * 1024 + c] = (__bf16)nv;
  }
}

// ---------------- gate: 4 tokens/block, gw in LDS, fp32 LN2 recompute, top2 -> eidx/wpair (NO atomics)
__global__ __launch_bounds__(256)
void gate_k(const float* __restrict__ h, const float* __restrict__ ln2s, const float* __restrict__ ln2b,
            const float* __restrict__ mods, const float* __restrict__ gw,
            int* __restrict__ eidx, float* __restrict__ wpair){
  __shared__ float gws[8192];
  int tid = threadIdx.x;
  #pragma unroll
  for (int i = 0; i < 8; i++){
    int idx = tid + i * 256;
    *(float4*)&gws[idx * 4] = *(const float4*)&gw[idx * 4];
  }
  __syncthreads();
  int wv = tid >> 6, lane = tid & 63;
  int tok = blockIdx.x * 4 + wv;
  int b = tok >> 10;
  float4 xv[4]; float s = 0.f, s2 = 0.f;
  #pragma unroll
  for (int ch = 0; ch < 4; ch++){
    float4 v = *(const float4*)&h[(long)tok * 1024 + ch * 256 + lane * 4];
    xv[ch] = v;
    s  += v.x + v.y + v.z + v.w;
    s2 += v.x * v.x + v.y * v.y + v.z * v.z + v.w * v.w;
  }
  s = wred_sum(s); s2 = wred_sum(s2);
  float mean = s * (1.f / 1024.f);
  float var  = s2 * (1.f / 1024.f) - mean * mean;
  float inv  = rsqrtf(var + 1e-6f);
  float lg[8];
  #pragma unroll
  for (int e = 0; e < 8; e++) lg[e] = 0.f;
  #pragma unroll
  for (int ch = 0; ch < 4; ch++){
    int c = ch * 256 + lane * 4;
    float4 s4  = *(const float4*)&ln2s[c];
    float4 b4  = *(const float4*)&ln2b[c];
    float4 sc4 = *(const float4*)&mods[b * 6144 + 4096 + c];
    float4 sh4 = *(const float4*)&mods[b * 6144 + 3072 + c];
    float n0 = ((xv[ch].x - mean) * inv * s4.x + b4.x) * (1.f + sc4.x) + sh4.x;
    float n1 = ((xv[ch].y - mean) * inv * s4.y + b4.y) * (1.f + sc4.y) + sh4.y;
    float n2 = ((xv[ch].z - mean) * inv * s4.z + b4.z) * (1.f + sc4.z) + sh4.z;
    float n3 = ((xv[ch].w - mean) * inv * s4.w + b4.w) * (1.f + sc4.w) + sh4.w;
    #pragma unroll
    for (int e = 0; e < 8; e++){
      float4 g4 = *(const float4*)&gws[e * 1024 + c];
      lg[e] += n0 * g4.x + n1 * g4.y + n2 * g4.z + n3 * g4.w;
    }
  }
  #pragma unroll
  for (int e = 0; e < 8; e++) lg[e] = wred_sum(lg[e]);
  if (lane == 0){
    float mx = lg[0];
    #pragma unroll
    for (int e = 1; e < 8; e++) mx = fmaxf(mx, lg[e]);
    float p[8], ss = 0.f;
    #pragma unroll
    for (int e = 0; e < 8; e++){ p[e] = expf(lg[e] - mx); ss += p[e]; }
    #pragma unroll
    for (int e = 0; e < 8; e++) p[e] /= ss;
    int i0 = 0; float b0 = p[0];
    #pragma unroll
    for (int e = 1; e < 8; e++) if (p[e] > b0){ b0 = p[e]; i0 = e; }
    int i1 = -1; float b1 = -1.f;
    #pragma unroll
    for (int e = 0; e < 8; e++) if (e != i0 && p[e] > b1){ b1 = p[e]; i1 = e; }
    float dn = b0 + b1 + 1e-20f;
    eidx[tok * 2]     = i0; wpair[tok * 2]     = b0 / dn;
    eidx[tok * 2 + 1] = i1; wpair[tok * 2 + 1] = b1 / dn;
  }
}

// ---------------- build routing lists: 1 block per expert, ordered ballot compaction
__global__ __launch_bounds__(256)
void build_k(const int* __restrict__ eidx, int* __restrict__ counts, int* __restrict__ lists){
  int e = blockIdx.x;
  int tid = threadIdx.x, wv = tid >> 6, lane = tid & 63;
  __shared__ int base;
  __shared__ int woff[4];
  if (tid == 0) base = 0;
  __syncthreads();
  for (int it = 0; it < 32; ++it){
    int i = it * 256 + tid;
    bool m = (eidx[i] == e);
    unsigned long long bal = __ballot(m);
    int prefix = __popcll(bal & ((1ull << lane) - 1ull));
    if (lane == 0) woff[wv] = __popcll(bal);
    __syncthreads();
    int off = base;
    #pragma unroll
    for (int k = 0; k < 4; k++) if (k < wv) off += woff[k];
    if (m) lists[e * 4096 + off + prefix] = i;
    __syncthreads();
    if (tid == 0) base += woff[0] + woff[1] + woff[2] + woff[3];
    __syncthreads();
  }
  if (tid == 0) counts[e] = base;
}

// ---------------- flash attention: 128 q-rows/block, exp2 softmax, defer-max, l via MFMA(B=ones)
__global__ __launch_bounds__(256)
void attn_k(const __bf16* __restrict__ qkv, __bf16* __restrict__ og){
  int bh = blockIdx.y; int bb = bh >> 4, hn = bh & 15;
  int q0 = blockIdx.x * 128;
  long tokbase = (long)bb * 1024;
  int hd0 = hn * 64;
  int tid = threadIdx.x; int w = tid >> 6; int lane = tid & 63;

  __shared__ __bf16 Ks[64][76];
  __shared__ __bf16 Vt[64][76];
  __shared__ __bf16 Ps[4][32][76];

  const float QS = 0.125f * 1.44269504088896f;  // softmax scale * log2(e) -> exp2 domain
  bf16x8 qf[2][2];
  #pragma unroll
  for (int sub = 0; sub < 2; sub++){
    long qrow = tokbase + q0 + sub * 64 + w * 16 + (lane & 15);
    qf[sub][0] = *(const bf16x8*)&qkv[qrow * 3072 + hd0 + (lane >> 4) * 8];
    qf[sub][1] = *(const bf16x8*)&qkv[qrow * 3072 + hd0 + 32 + (lane >> 4) * 8];
    #pragma unroll
    for (int i = 0; i < 8; i++){
      qf[sub][0][i] = (__bf16)((float)qf[sub][0][i] * QS);
      qf[sub][1][i] = (__bf16)((float)qf[sub][1][i] * QS);
    }
  }

  __bf16 one_b = (__bf16)1.0f;
  bf16x8 one8 = (bf16x8){one_b, one_b, one_b, one_b, one_b, one_b, one_b, one_b};

  float m_r[2][4];
  f32x4 oa[2][4];
  f32x4 lacc[2];
  #pragma unroll
  for (int sub = 0; sub < 2; sub++){
    lacc[sub] = (f32x4){0.f, 0.f, 0.f, 0.f};
    #pragma unroll
    for (int r = 0; r < 4; r++) m_r[sub][r] = -1e30f;
    #pragma unroll
    for (int hb = 0; hb < 4; hb++) oa[sub][hb] = (f32x4){0.f, 0.f, 0.f, 0.f};
  }

  int dcol = tid & 63, rblk = tid >> 6;
  for (int t = 0; t < 16; t++){
    long kvbase = tokbase + t * 64;
    #pragma unroll
    for (int p = 0; p < 2; p++){
      int r = (tid >> 3) + p * 32;
      int c = (tid & 7) * 8;
      *(bf16x8*)&Ks[r][c] = *(const bf16x8*)&qkv[(kvbase + r) * 3072 + 1024 + hd0 + c];
    }
    // V^T staging: lane reads a head-dim column (coalesced across lanes), writes contiguous Vt chunk
    bf16x8 col0, col1;
    #pragma unroll
    for (int i = 0; i < 8; i++)
      col0[i] = qkv[(kvbase + rblk * 16 + i) * 3072 + 2048 + hd0 + dcol];
    #pragma unroll
    for (int i = 0; i < 8; i++)
      col1[i] = qkv[(kvbase + rblk * 16 + 8 + i) * 3072 + 2048 + hd0 + dcol];
    *(bf16x8*)&Vt[dcol][rblk * 16]     = col0;
    *(bf16x8*)&Vt[dcol][rblk * 16 + 8] = col1;
    __syncthreads();

    #pragma unroll
    for (int sub = 0; sub < 2; sub++){
      f32x4 sf[4];
      #pragma unroll
      for (int cb = 0; cb < 4; cb++){
        bf16x8 kf0 = *(const bf16x8*)&Ks[cb * 16 + (lane & 15)][(lane >> 4) * 8];
        bf16x8 kf1 = *(const bf16x8*)&Ks[cb * 16 + (lane & 15)][32 + (lane >> 4) * 8];
        f32x4 sacc = (f32x4){0.f, 0.f, 0.f, 0.f};
        sacc = __builtin_amdgcn_mfma_f32_16x16x32_bf16(qf[sub][0], kf0, sacc, 0, 0, 0);
        sacc = __builtin_amdgcn_mfma_f32_16x16x32_bf16(qf[sub][1], kf1, sacc, 0, 0, 0);
        sf[cb] = sacc;
      }
      float mxr[4]; float dmax = -1e30f;
      #pragma unroll
      for (int r = 0; r < 4; r++){
        float mx = fmaxf(fmaxf(sf[0][r], sf[1][r]), fmaxf(sf[2][r], sf[3][r]));
        #pragma unroll
        for (int d = 1; d < 16; d <<= 1) mx = fmaxf(mx, __shfl_xor(mx, d, 64));
        mxr[r] = mx;
        dmax = fmaxf(dmax, mx - m_r[sub][r]);
      }
      if (!__all(dmax <= 8.f)){  // defer-max: rescale only when max grew past threshold
        #pragma unroll
        for (int r = 0; r < 4; r++){
          float mn = fmaxf(m_r[sub][r], mxr[r]);
          float fr = __builtin_amdgcn_exp2f(m_r[sub][r] - mn);
          m_r[sub][r] = mn;
          lacc[sub][r] *= fr;
          #pragma unroll
          for (int hb = 0; hb < 4; hb++) oa[sub][hb][r] *= fr;
        }
      }
      #pragma unroll
      for (int cb = 0; cb < 4; cb++)
        #pragma unroll
        for (int r = 0; r < 4; r++)
          Ps[w][sub * 16 + (lane >> 4) * 4 + r][cb * 16 + (lane & 15)] =
            (__bf16)__builtin_amdgcn_exp2f(sf[cb][r] - m_r[sub][r]);
    }
    // Ps is wave-private: no barrier needed (compiler inserts lgkmcnt before reads)
    bf16x8 pf[2][2];
    #pragma unroll
    for (int sub = 0; sub < 2; sub++){
      pf[sub][0] = *(const bf16x8*)&Ps[w][sub * 16 + (lane & 15)][(lane >> 4) * 8];
      pf[sub][1] = *(const bf16x8*)&Ps[w][sub * 16 + (lane & 15)][32 + (lane >> 4) * 8];
      lacc[sub] = __builtin_amdgcn_mfma_f32_16x16x32_bf16(pf[sub][0], one8, lacc[sub], 0, 0, 0);
      lacc[sub] = __builtin_amdgcn_mfma_f32_16x16x32_bf16(pf[sub][1], one8, lacc[sub], 0, 0, 0);
    }
    #pragma unroll
    for (int hb = 0; hb < 4; hb++){
      bf16x8 vf0 = *(const bf16x8*)&Vt[hb * 16 + (lane & 15)][(lane >> 4) * 8];
      bf16x8 vf1 = *(const bf16x8*)&Vt[hb * 16 + (lane & 15)][32 + (lane >> 4) * 8];
      #pragma unroll
      for (int sub = 0; sub < 2; sub++){
        oa[sub][hb] = __builtin_amdgcn_mfma_f32_16x16x32_bf16(pf[sub][0], vf0, oa[sub][hb], 0, 0, 0);
        oa[sub][hb] = __builtin_amdgcn_mfma_f32_16x16x32_bf16(pf[sub][1], vf1, oa[sub][hb], 0, 0, 0);
      }
    }
    __syncthreads();
  }
  #pragma unroll
  for (int sub = 0; sub < 2; sub++)
    #pragma unroll
    for (int hb = 0; hb < 4; hb++)
      #pragma unroll
      for (int r = 0; r < 4; r++){
        long row = tokbase + q0 + sub * 64 + w * 16 + (lane >> 4) * 4 + r;
        float val = oa[sub][hb][r] / lacc[sub][r];
        og[row * 1024 + hd0 + hb * 16 + (lane & 15)] = (__bf16)val;
      }
}

// ---------------- m97-style GEMM: global_load_lds + XOR block-swizzle (both sides)
// C[M,N] = A[M,K] @ Bt[N,K]^T, 128x128 tile, BK=64, 4 waves
// EPI: 0=store bf16, 1=gelu->bf16, 2=h=resid+gate*acc (f32), 3=store f32, 4=atomicAdd(w*acc)
// GMODE: 0=linear, 1=expert GEMM1 (src=pair>>1, dst=pair), 2=expert GEMM2 (src=pair, dst=pair>>1)
template<int EPI, int GMODE>
__global__ __launch_bounds__(256)
void gemm_k(const __bf16* __restrict__ A, int lda,
            const __bf16* __restrict__ Bt, int K, long bstride,
            const int* __restrict__ lists, const int* __restrict__ counts,
            __bf16* __restrict__ outb, int ldo,
            float* __restrict__ outf,
            const float* __restrict__ resid,
            const float* __restrict__ mods, int mod_off,
            const float* __restrict__ wpair){
  int e = blockIdx.z;
  int cnt = 1 << 30;
  const int* list = nullptr;
  if (GMODE){
    cnt = counts[e];
    if ((int)blockIdx.y * 128 >= cnt) return;
    list = lists + e * 4096;
    Bt += (long)e * bstride;
  }
  int row0 = blockIdx.y * 128;
  int n0 = blockIdx.x * 128;
  int tid = threadIdx.x;
  int lane = tid & 63, w = tid >> 6;
  int wr = (w >> 1) * 64, wc = (w & 1) * 64;

  __shared__ __bf16 As[128 * 64];
  __shared__ __bf16 Bs[128 * 64];

  f32x4 acc[4][4];
  #pragma unroll
  for (int m = 0; m < 4; m++)
    #pragma unroll
    for (int n = 0; n < 4; n++) acc[m][n] = (f32x4){0.f, 0.f, 0.f, 0.f};

  long aoff[4]; const __bf16* bptr[4];
  #pragma unroll
  for (int j = 0; j < 4; j++){
    int r = w * 32 + j * 8 + (lane >> 3);
    int scb = (lane & 7) ^ (r & 7);
    int gr = row0 + r;
    int srcr;
    if (GMODE == 0) srcr = gr;
    else if (gr < cnt){ int pv = list[gr]; srcr = (GMODE == 1) ? (pv >> 1) : pv; }
    else { int pv = list[0]; srcr = (GMODE == 1) ? (pv >> 1) : pv; }  // harmless garbage row
    aoff[j] = (long)srcr * lda + scb * 8;
    bptr[j] = Bt + (long)(n0 + r) * K + scb * 8;
  }
  const int nk = K / 64;
  for (int kt = 0; kt < nk; ++kt){
    int k0 = kt * 64;
    #pragma unroll
    for (int j = 0; j < 4; j++){
      gload_lds16(A + aoff[j] + k0, &As[(w * 32 + j * 8) * 64]);
      gload_lds16(bptr[j] + k0,     &Bs[(w * 32 + j * 8) * 64]);
    }
    __syncthreads();
    #pragma unroll
    for (int ks = 0; ks < 2; ++ks){
      bf16x8 af[4], bfr[4];
      #pragma unroll
      for (int m = 0; m < 4; m++){
        int r = wr + m * 16 + (lane & 15);
        int blk = (ks * 4 + (lane >> 4)) ^ (r & 7);
        af[m] = *(const bf16x8*)&As[r * 64 + blk * 8];
      }
      #pragma unroll
      for (int n = 0; n < 4; n++){
        int r = wc + n * 16 + (lane & 15);
        int blk = (ks * 4 + (lane >> 4)) ^ (r & 7);
        bfr[n] = *(const bf16x8*)&Bs[r * 64 + blk * 8];
      }
      #pragma unroll
      for (int m = 0; m < 4; m++)
        #pragma unroll
        for (int n = 0; n < 4; n++)
          acc[m][n] = __builtin_amdgcn_mfma_f32_16x16x32_bf16(af[m], bfr[n], acc[m][n], 0, 0, 0);
    }
    __syncthreads();
  }
  #pragma unroll
  for (int m = 0; m < 4; m++){
    #pragma unroll
    for (int r = 0; r < 4; r++){
      int rl = wr + m * 16 + (lane >> 4) * 4 + r;
      int grow = row0 + rl;
      if (GMODE && grow >= cnt) continue;
      #pragma unroll
      for (int n = 0; n < 4; n++){
        int col = n0 + wc + n * 16 + (lane & 15);
        float v = acc[m][n][r];
        if (EPI == 0){
          outb[(long)grow * ldo + col] = (__bf16)v;
        } else if (EPI == 1){
          int dst = (GMODE == 1) ? list[grow] : grow;
          outb[(long)dst * ldo + col] = (__bf16)gelu_t(v);
        } else if (EPI == 2){
          int b = grow >> 10;
          outf[(long)grow * 1024 + col] = resid[(long)grow * 1024 + col] + mods[b * 6144 + mod_off + col] * v;
        } else if (EPI == 3){
          outf[(long)grow * 1024 + col] = v;
        } else if (EPI == 4){
          int pv = list[grow];
          atomicAdd(&outf[(long)(pv >> 1) * 1024 + col], wpair[pv] * v);
        }
      }
    }
  }
}

// ---------------- final: out = h + gate_mlp * y
__global__ __launch_bounds__(256)
void final_k(const float* __restrict__ h, const float* __restrict__ y,
             const float* __restrict__ mods, float* __restrict__ out){
  int i = blockIdx.x * 256 + threadIdx.x;
  long base = (long)i * 4;
  int row = (int)(base >> 10); int b = row >> 10; int c = (int)(base & 1023);
  float4 hv = *(const float4*)&h[base];
  float4 yv = *(const float4*)&y[base];
  const float* g = &mods[b * 6144 + 5120 + c];
  float4 o;
  o.x = hv.x + g[0] * yv.x;
  o.y = hv.y + g[1] * yv.y;
  o.z = hv.z + g[2] * yv.z;
  o.w = hv.w + g[3] * yv.w;
  *(float4*)&out[base] = o;
}

extern "C" void kernel_launch(void* const* d_in, const int* in_sizes, int n_in,
                              void* d_out, int out_size, void* d_ws, size_t ws_size,
                              hipStream_t stream){
  const float* hidden = (const float*)d_in[0];
  const float* cond   = (const float*)d_in[1];
  const float* adaW   = (const float*)d_in[2];
  const float* ln1s   = (const float*)d_in[3];
  const float* ln1b   = (const float*)d_in[4];
  const float* ln2s   = (const float*)d_in[5];
  const float* ln2b   = (const float*)d_in[6];
  const float* Wq     = (const float*)d_in[7];
  const float* Wk     = (const float*)d_in[8];
  const float* Wv     = (const float*)d_in[9];
  const float* Wo     = (const float*)d_in[10];
  const float* gatek  = (const float*)d_in[11];
  const float* We1    = (const float*)d_in[12];
  const float* We2    = (const float*)d_in[13];
  const float* Ws1    = (const float*)d_in[14];
  const float* Ws2    = (const float*)d_in[15];
  float* out = (float*)d_out;

  const size_t MB = 1024 * 1024;
  char* W = (char*)d_ws;
  size_t off = 0;
  auto take = [&](size_t b) -> void* {
    void* p = W + off;
    off += (b + 255) & ~((size_t)255);
    return p;
  };
  float*  mods   = (float*) take(4 * 6144 * sizeof(float));
  __bf16* qkvT   = (__bf16*)take(6 * MB);   // [3072][1024]
  __bf16* WoT    = (__bf16*)take(2 * MB);
  __bf16* Ws1T   = (__bf16*)take(4 * MB);
  __bf16* Ws2T   = (__bf16*)take(4 * MB);
  __bf16* We1T   = (__bf16*)take(16 * MB);
  __bf16* We2T   = (__bf16*)take(16 * MB);
  __bf16* n1     = (__bf16*)take(8 * MB);   // [4096][1024]
  __bf16* ab     = (__bf16*)take(8 * MB);   // attn out [4096][1024]  (n1+ab contiguous = EH alias)
  __bf16* qkv    = (__bf16*)take(24 * MB);  // [4096][3072]
  float*  hb     = (float*) take(16 * MB);
  __bf16* n2     = (__bf16*)take(8 * MB);
  float*  yb     = (float*) take(16 * MB);
  int*    counts = (int*)   take(256);
  int*    lists  = (int*)   take(8 * 4096 * 4);
  float*  wpair  = (float*) take(8192 * 4);
  int*    eidx   = (int*)   take(8192 * 4);
  __bf16* EH = n1;   // [8192][1024] = 16 MB, aliases n1+ab (both dead by expert GEMM1)
  __bf16* SH = qkv;  // [4096][2048] = 16 MB, aliases qkv (dead after attention)

  dim3 blk(256);

  hipMemsetAsync(mods, 0, 4 * 6144 * sizeof(float), stream);

  // weight transposes (fp32 -> bf16 [N][K]); QKV packed into one [3072][1024]
  transpose_cvt<<<dim3(32, 32, 1), blk, 0, stream>>>(Wq,  qkvT,              1024, 1024);
  transpose_cvt<<<dim3(32, 32, 1), blk, 0, stream>>>(Wk,  qkvT + 1024*1024,  1024, 1024);
  transpose_cvt<<<dim3(32, 32, 1), blk, 0, stream>>>(Wv,  qkvT + 2048*1024,  1024, 1024);
  transpose_cvt<<<dim3(32, 32, 1), blk, 0, stream>>>(Wo,  WoT,  1024, 1024);
  transpose_cvt<<<dim3(64, 32, 1), blk, 0, stream>>>(Ws1, Ws1T, 1024, 2048);
  transpose_cvt<<<dim3(32, 64, 1), blk, 0, stream>>>(Ws2, Ws2T, 2048, 1024);
  transpose_cvt<<<dim3(32, 32, 8), blk, 0, stream>>>(We1, We1T, 1024, 1024);
  transpose_cvt<<<dim3(32, 32, 8), blk, 0, stream>>>(We2, We2T, 1024, 1024);

  adaln_k<<<dim3(6, 4, 4), blk, 0, stream>>>(cond, adaW, mods);

  // LN1 + modulate (shift_msa@0, scale_msa@1024)
  ln_mod<<<4096, blk, 0, stream>>>(hidden, ln1s, ln1b, mods, 0, 1024, n1);

  // fused QKV projection: [4096][3072]
  gemm_k<0, 0><<<dim3(24, 32, 1), blk, 0, stream>>>(n1, 1024, qkvT, 1024, 0, nullptr, nullptr, qkv, 3072, nullptr, nullptr, nullptr, 0, nullptr);

  attn_k<<<dim3(8, 64, 1), blk, 0, stream>>>(qkv, ab);

  // h = hidden + gate_msa (mods@2048) * (attn @ Wo)
  gemm_k<2, 0><<<dim3(8, 32, 1), blk, 0, stream>>>(ab, 1024, WoT, 1024, 0, nullptr, nullptr, nullptr, 0, hb, hidden, mods, 2048, nullptr);

  // LN2 + modulate (shift_mlp@3072, scale_mlp@4096)
  ln_mod<<<4096, blk, 0, stream>>>(hb, ln2s, ln2b, mods, 3072, 4096, n2);

  // MoE gate (fp32 recompute of normed2 from h) + ordered list build
  gate_k<<<1024, blk, 0, stream>>>(hb, ln2s, ln2b, mods, gatek, eidx, wpair);
  build_k<<<8, blk, 0, stream>>>(eidx, counts, lists);

  // shared experts: SH = gelu(n2 @ Ws1); y = SH @ Ws2
  gemm_k<1, 0><<<dim3(16, 32, 1), blk, 0, stream>>>(n2, 1024, Ws1T, 1024, 0, nullptr, nullptr, SH, 2048, nullptr, nullptr, nullptr, 0, nullptr);
  gemm_k<3, 0><<<dim3(8, 32, 1), blk, 0, stream>>>(SH, 2048, Ws2T, 2048, 0, nullptr, nullptr, nullptr, 0, yb, nullptr, nullptr, 0, nullptr);

  // routed experts (top-2 only): EH = gelu(gather(n2) @ We1[e]); y += w * (EH @ We2[e])
  gemm_k<1, 1><<<dim3(8, 32, 8), blk, 0, stream>>>(n2, 1024, We1T, 1024, 1048576, lists, counts, EH, 1024, nullptr, nullptr, nullptr, 0, nullptr);
  gemm_k<4, 2><<<dim3(8, 32, 8), blk, 0, stream>>>(EH, 1024, We2T, 1024, 1048576, lists, counts, nullptr, 0, yb, nullptr, nullptr, 0, wpair);

  // out = h + gate_mlp (mods@5120) * y
  final_k<<<4096, blk, 0, stream>>>(hb, yb, mods, out);

  (void)in_sizes; (void)n_in; (void)out_size; (void)ws_size;
}

// Round 5
// 560.870 us; speedup vs baseline: 1.4642x; 1.0014x over previous
//
#include <hip/hip_runtime.h>

typedef __bf16 bf16x8 __attribute__((ext_vector_type(8)));
typedef __bf16 bf16x4 __attribute__((ext_vector_type(4)));
typedef float  f32x4  __attribute__((ext_vector_type(4)));

__device__ inline float wred_sum(float v){
  #pragma unroll
  for (int d = 1; d < 64; d <<= 1) v += __shfl_xor(v, d, 64);
  return v;
}

__device__ inline float gelu_t(float x){
  const float c0 = 0.7978845608028654f;
  float t = tanhf(c0 * (x + 0.044715f * x * x * x));
  return 0.5f * x * (1.0f + t);
}

__device__ __forceinline__ void gload_lds16(const __bf16* g, __bf16* l){
  __builtin_amdgcn_global_load_lds((const __attribute__((address_space(1))) void*)g,
                                   (__attribute__((address_space(3))) void*)l, 16, 0, 0);
}

// ---------------- ALL weight transposes in one launch: 24 slabs of [1024][1024] f32 -> bf16^T
__global__ __launch_bounds__(256)
void transpose_all(const float* __restrict__ Wq, const float* __restrict__ Wk,
                   const float* __restrict__ Wv, const float* __restrict__ Wo,
                   const float* __restrict__ Ws1, const float* __restrict__ Ws2,
                   const float* __restrict__ We1, const float* __restrict__ We2,
                   __bf16* __restrict__ qkvT, __bf16* __restrict__ WoT,
                   __bf16* __restrict__ Ws1T, __bf16* __restrict__ Ws2T,
                   __bf16* __restrict__ We1T, __bf16* __restrict__ We2T){
  int z = blockIdx.z;
  const float* src; long ss; __bf16* dst; long ds;
  const long M1 = 1024 * 1024;
  if (z < 3)      { src = (z == 0 ? Wq : z == 1 ? Wk : Wv); ss = 1024; dst = qkvT + (long)z * M1; ds = 1024; }
  else if (z == 3){ src = Wo; ss = 1024; dst = WoT; ds = 1024; }
  else if (z < 6) { int ch = z - 4; src = Ws1 + ch * 1024; ss = 2048; dst = Ws1T + (long)ch * M1; ds = 1024; }
  else if (z < 8) { int rh = z - 6; src = Ws2 + (long)rh * M1; ss = 1024; dst = Ws2T + rh * 1024; ds = 2048; }
  else if (z < 16){ int e = z - 8;  src = We1 + (long)e * M1; ss = 1024; dst = We1T + (long)e * M1; ds = 1024; }
  else            { int e = z - 16; src = We2 + (long)e * M1; ss = 1024; dst = We2T + (long)e * M1; ds = 1024; }
  __shared__ float t[32][33];
  int r0 = blockIdx.y * 32, c0 = blockIdx.x * 32;
  int tid = threadIdx.x;
  int tr = tid >> 3, tc = (tid & 7) * 4;
  float4 vv = *(const float4*)&src[(long)(r0 + tr) * ss + c0 + tc];
  t[tr][tc + 0] = vv.x; t[tr][tc + 1] = vv.y; t[tr][tc + 2] = vv.z; t[tr][tc + 3] = vv.w;
  __syncthreads();
  int oc = tid >> 3, orr = (tid & 7) * 4;
  bf16x4 o4;
  #pragma unroll
  for (int i = 0; i < 4; i++) o4[i] = (__bf16)t[orr + i][oc];
  *(bf16x4*)&dst[(long)(c0 + oc) * ds + r0 + orr] = o4;
}

// ---------------- adaLN: split-K atomics, all 4 batches per W element (W read once)
__global__ __launch_bounds__(256)
void adaln_k(const float* __restrict__ cond, const float* __restrict__ W, float* __restrict__ mods){
  int col = blockIdx.x * 256 + threadIdx.x;
  int kc  = blockIdx.y;
  __shared__ float sc[4][256];
  for (int i = threadIdx.x; i < 1024; i += 256){
    int b = i >> 8, r = i & 255;
    float x = cond[b * 1024 + kc * 256 + r];
    sc[b][r] = x / (1.f + expf(-x));
  }
  __syncthreads();
  float a0 = 0.f, a1 = 0.f, a2 = 0.f, a3 = 0.f;
  #pragma unroll 4
  for (int i = 0; i < 256; i++){
    float wv = W[(long)(kc * 256 + i) * 6144 + col];
    a0 += sc[0][i] * wv; a1 += sc[1][i] * wv;
    a2 += sc[2][i] * wv; a3 += sc[3][i] * wv;
  }
  atomicAdd(&mods[0 * 6144 + col], a0);
  atomicAdd(&mods[1 * 6144 + col], a1);
  atomicAdd(&mods[2 * 6144 + col], a2);
  atomicAdd(&mods[3 * 6144 + col], a3);
}

// ---------------- LayerNorm + modulate -> bf16 (LN1)
__global__ __launch_bounds__(256)
void ln_mod(const float* __restrict__ x, const float* __restrict__ sc, const float* __restrict__ bi,
            const float* __restrict__ mods, int shift_off, int scale_off, __bf16* __restrict__ out){
  int row = blockIdx.x, tid = threadIdx.x, b = row >> 10;
  float4 xv = *(const float4*)&x[(long)row * 1024 + tid * 4];
  float s  = xv.x + xv.y + xv.z + xv.w;
  float s2 = xv.x * xv.x + xv.y * xv.y + xv.z * xv.z + xv.w * xv.w;
  s = wred_sum(s); s2 = wred_sum(s2);
  __shared__ float ssum[4], ssum2[4];
  int w = tid >> 6;
  if ((tid & 63) == 0){ ssum[w] = s; ssum2[w] = s2; }
  __syncthreads();
  s = ssum[0] + ssum[1] + ssum[2] + ssum[3];
  s2 = ssum2[0] + ssum2[1] + ssum2[2] + ssum2[3];
  float mean = s * (1.f / 1024.f);
  float var  = s2 * (1.f / 1024.f) - mean * mean;
  float inv  = rsqrtf(var + 1e-6f);
  const float xa[4] = {xv.x, xv.y, xv.z, xv.w};
  #pragma unroll
  for (int i = 0; i < 4; i++){
    int c = tid * 4 + i;
    float nv = (xa[i] - mean) * inv * sc[c] + bi[c];
    nv = nv * (1.f + mods[b * 6144 + scale_off + c]) + mods[b * 6144 + shift_off + c];
    out[(long)row * 1024 + c] = (__bf16)nv;
  }
}

// ---------------- gate: LN2 recompute in fp32, writes n2 (bf16) + top2 eidx/wpair. NO atomics.
__global__ __launch_bounds__(256)
void gate_k(const float* __restrict__ h, const float* __restrict__ ln2s, const float* __restrict__ ln2b,
            const float* __restrict__ mods, const float* __restrict__ gw,
            int* __restrict__ eidx, float* __restrict__ wpair, __bf16* __restrict__ n2o){
  __shared__ float gws[8192];
  int tid = threadIdx.x;
  #pragma unroll
  for (int i = 0; i < 8; i++){
    int idx = tid + i * 256;
    *(float4*)&gws[idx * 4] = *(const float4*)&gw[idx * 4];
  }
  __syncthreads();
  int wv = tid >> 6, lane = tid & 63;
  int tok = blockIdx.x * 4 + wv;
  int b = tok >> 10;
  float4 xv[4]; float s = 0.f, s2 = 0.f;
  #pragma unroll
  for (int ch = 0; ch < 4; ch++){
    float4 v = *(const float4*)&h[(long)tok * 1024 + ch * 256 + lane * 4];
    xv[ch] = v;
    s  += v.x + v.y + v.z + v.w;
    s2 += v.x * v.x + v.y * v.y + v.z * v.z + v.w * v.w;
  }
  s = wred_sum(s); s2 = wred_sum(s2);
  float mean = s * (1.f / 1024.f);
  float var  = s2 * (1.f / 1024.f) - mean * mean;
  float inv  = rsqrtf(var + 1e-6f);
  float lg[8];
  #pragma unroll
  for (int e = 0; e < 8; e++) lg[e] = 0.f;
  #pragma unroll
  for (int ch = 0; ch < 4; ch++){
    int c = ch * 256 + lane * 4;
    float4 s4  = *(const float4*)&ln2s[c];
    float4 b4  = *(const float4*)&ln2b[c];
    float4 sc4 = *(const float4*)&mods[b * 6144 + 4096 + c];
    float4 sh4 = *(const float4*)&mods[b * 6144 + 3072 + c];
    float v0 = ((xv[ch].x - mean) * inv * s4.x + b4.x) * (1.f + sc4.x) + sh4.x;
    float v1 = ((xv[ch].y - mean) * inv * s4.y + b4.y) * (1.f + sc4.y) + sh4.y;
    float v2 = ((xv[ch].z - mean) * inv * s4.z + b4.z) * (1.f + sc4.z) + sh4.z;
    float v3 = ((xv[ch].w - mean) * inv * s4.w + b4.w) * (1.f + sc4.w) + sh4.w;
    *(bf16x4*)&n2o[(long)tok * 1024 + c] = (bf16x4){(__bf16)v0, (__bf16)v1, (__bf16)v2, (__bf16)v3};
    #pragma unroll
    for (int e = 0; e < 8; e++){
      float4 g4 = *(const float4*)&gws[e * 1024 + c];
      lg[e] += v0 * g4.x + v1 * g4.y + v2 * g4.z + v3 * g4.w;
    }
  }
  #pragma unroll
  for (int e = 0; e < 8; e++) lg[e] = wred_sum(lg[e]);
  if (lane == 0){
    float mx = lg[0];
    #pragma unroll
    for (int e = 1; e < 8; e++) mx = fmaxf(mx, lg[e]);
    float p[8], ss = 0.f;
    #pragma unroll
    for (int e = 0; e < 8; e++){ p[e] = expf(lg[e] - mx); ss += p[e]; }
    #pragma unroll
    for (int e = 0; e < 8; e++) p[e] /= ss;
    int i0 = 0; float b0 = p[0];
    #pragma unroll
    for (int e = 1; e < 8; e++) if (p[e] > b0){ b0 = p[e]; i0 = e; }
    int i1 = -1; float b1 = -1.f;
    #pragma unroll
    for (int e = 0; e < 8; e++) if (e != i0 && p[e] > b1){ b1 = p[e]; i1 = e; }
    float dn = b0 + b1 + 1e-20f;
    eidx[tok * 2]     = i0; wpair[tok * 2]     = b0 / dn;
    eidx[tok * 2 + 1] = i1; wpair[tok * 2 + 1] = b1 / dn;
  }
}

// ---------------- build routing lists: 1 block per expert, ordered ballot compaction
__global__ __launch_bounds__(256)
void build_k(const int* __restrict__ eidx, int* __restrict__ counts, int* __restrict__ lists){
  int e = blockIdx.x;
  int tid = threadIdx.x, wv = tid >> 6, lane = tid & 63;
  __shared__ int base;
  __shared__ int woff[4];
  if (tid == 0) base = 0;
  __syncthreads();
  for (int it = 0; it < 32; ++it){
    int i = it * 256 + tid;
    bool m = (eidx[i] == e);
    unsigned long long bal = __ballot(m);
    int prefix = __popcll(bal & ((1ull << lane) - 1ull));
    if (lane == 0) woff[wv] = __popcll(bal);
    __syncthreads();
    int off = base;
    #pragma unroll
    for (int k = 0; k < 4; k++) if (k < wv) off += woff[k];
    if (m) lists[e * 4096 + off + prefix] = i;
    __syncthreads();
    if (tid == 0) base += woff[0] + woff[1] + woff[2] + woff[3];
    __syncthreads();
  }
  if (tid == 0) counts[e] = base;
}

// ---------------- flash attention: 128 q-rows/block, XCD-grouped (b,h), exp2+defer-max
__global__ __launch_bounds__(256)
void attn_k(const __bf16* __restrict__ qkv, __bf16* __restrict__ og){
  // bijective remap: all 8 q-blocks of one (b,h) land on the same XCD (p%8 fixed per bh group)
  int p = blockIdx.x + blockIdx.y * 8;          // gridDim.x == 8
  int qblk = (p >> 3) & 7;
  int bh   = (p & 7) + ((p >> 6) << 3);
  int bb = bh >> 4, hn = bh & 15;
  int q0 = qblk * 128;
  long tokbase = (long)bb * 1024;
  int hd0 = hn * 64;
  int tid = threadIdx.x; int w = tid >> 6; int lane = tid & 63;

  __shared__ __bf16 Ks[64][76];
  __shared__ __bf16 Vt[64][76];
  __shared__ __bf16 Ps[4][32][76];

  const float QS = 0.125f * 1.44269504088896f;  // softmax scale * log2(e) -> exp2 domain
  bf16x8 qf[2][2];
  #pragma unroll
  for (int sub = 0; sub < 2; sub++){
    long qrow = tokbase + q0 + sub * 64 + w * 16 + (lane & 15);
    qf[sub][0] = *(const bf16x8*)&qkv[qrow * 3072 + hd0 + (lane >> 4) * 8];
    qf[sub][1] = *(const bf16x8*)&qkv[qrow * 3072 + hd0 + 32 + (lane >> 4) * 8];
    #pragma unroll
    for (int i = 0; i < 8; i++){
      qf[sub][0][i] = (__bf16)((float)qf[sub][0][i] * QS);
      qf[sub][1][i] = (__bf16)((float)qf[sub][1][i] * QS);
    }
  }

  __bf16 one_b = (__bf16)1.0f;
  bf16x8 one8 = (bf16x8){one_b, one_b, one_b, one_b, one_b, one_b, one_b, one_b};

  float m_r[2][4];
  f32x4 oa[2][4];
  f32x4 lacc[2];
  #pragma unroll
  for (int sub = 0; sub < 2; sub++){
    lacc[sub] = (f32x4){0.f, 0.f, 0.f, 0.f};
    #pragma unroll
    for (int r = 0; r < 4; r++) m_r[sub][r] = -1e30f;
    #pragma unroll
    for (int hb = 0; hb < 4; hb++) oa[sub][hb] = (f32x4){0.f, 0.f, 0.f, 0.f};
  }

  int dcol = tid & 63, rblk = tid >> 6;
  for (int t = 0; t < 16; t++){
    long kvbase = tokbase + t * 64;
    #pragma unroll
    for (int pp = 0; pp < 2; pp++){
      int r = (tid >> 3) + pp * 32;
      int c = (tid & 7) * 8;
      *(bf16x8*)&Ks[r][c] = *(const bf16x8*)&qkv[(kvbase + r) * 3072 + 1024 + hd0 + c];
    }
    bf16x8 col0, col1;
    #pragma unroll
    for (int i = 0; i < 8; i++)
      col0[i] = qkv[(kvbase + rblk * 16 + i) * 3072 + 2048 + hd0 + dcol];
    #pragma unroll
    for (int i = 0; i < 8; i++)
      col1[i] = qkv[(kvbase + rblk * 16 + 8 + i) * 3072 + 2048 + hd0 + dcol];
    *(bf16x8*)&Vt[dcol][rblk * 16]     = col0;
    *(bf16x8*)&Vt[dcol][rblk * 16 + 8] = col1;
    __syncthreads();

    #pragma unroll
    for (int sub = 0; sub < 2; sub++){
      f32x4 sf[4];
      #pragma unroll
      for (int cb = 0; cb < 4; cb++){
        bf16x8 kf0 = *(const bf16x8*)&Ks[cb * 16 + (lane & 15)][(lane >> 4) * 8];
        bf16x8 kf1 = *(const bf16x8*)&Ks[cb * 16 + (lane & 15)][32 + (lane >> 4) * 8];
        f32x4 sacc = (f32x4){0.f, 0.f, 0.f, 0.f};
        sacc = __builtin_amdgcn_mfma_f32_16x16x32_bf16(qf[sub][0], kf0, sacc, 0, 0, 0);
        sacc = __builtin_amdgcn_mfma_f32_16x16x32_bf16(qf[sub][1], kf1, sacc, 0, 0, 0);
        sf[cb] = sacc;
      }
      float mxr[4]; float dmax = -1e30f;
      #pragma unroll
      for (int r = 0; r < 4; r++){
        float mx = fmaxf(fmaxf(sf[0][r], sf[1][r]), fmaxf(sf[2][r], sf[3][r]));
        #pragma unroll
        for (int d = 1; d < 16; d <<= 1) mx = fmaxf(mx, __shfl_xor(mx, d, 64));
        mxr[r] = mx;
        dmax = fmaxf(dmax, mx - m_r[sub][r]);
      }
      if (!__all(dmax <= 8.f)){
        #pragma unroll
        for (int r = 0; r < 4; r++){
          float mn = fmaxf(m_r[sub][r], mxr[r]);
          float fr = __builtin_amdgcn_exp2f(m_r[sub][r] - mn);
          m_r[sub][r] = mn;
          lacc[sub][r] *= fr;
          #pragma unroll
          for (int hb = 0; hb < 4; hb++) oa[sub][hb][r] *= fr;
        }
      }
      #pragma unroll
      for (int cb = 0; cb < 4; cb++)
        #pragma unroll
        for (int r = 0; r < 4; r++)
          Ps[w][sub * 16 + (lane >> 4) * 4 + r][cb * 16 + (lane & 15)] =
            (__bf16)__builtin_amdgcn_exp2f(sf[cb][r] - m_r[sub][r]);
    }
    bf16x8 pf[2][2];
    #pragma unroll
    for (int sub = 0; sub < 2; sub++){
      pf[sub][0] = *(const bf16x8*)&Ps[w][sub * 16 + (lane & 15)][(lane >> 4) * 8];
      pf[sub][1] = *(const bf16x8*)&Ps[w][sub * 16 + (lane & 15)][32 + (lane >> 4) * 8];
      lacc[sub] = __builtin_amdgcn_mfma_f32_16x16x32_bf16(pf[sub][0], one8, lacc[sub], 0, 0, 0);
      lacc[sub] = __builtin_amdgcn_mfma_f32_16x16x32_bf16(pf[sub][1], one8, lacc[sub], 0, 0, 0);
    }
    #pragma unroll
    for (int hb = 0; hb < 4; hb++){
      bf16x8 vf0 = *(const bf16x8*)&Vt[hb * 16 + (lane & 15)][(lane >> 4) * 8];
      bf16x8 vf1 = *(const bf16x8*)&Vt[hb * 16 + (lane & 15)][32 + (lane >> 4) * 8];
      #pragma unroll
      for (int sub = 0; sub < 2; sub++){
        oa[sub][hb] = __builtin_amdgcn_mfma_f32_16x16x32_bf16(pf[sub][0], vf0, oa[sub][hb], 0, 0, 0);
        oa[sub][hb] = __builtin_amdgcn_mfma_f32_16x16x32_bf16(pf[sub][1], vf1, oa[sub][hb], 0, 0, 0);
      }
    }
    __syncthreads();
  }
  #pragma unroll
  for (int sub = 0; sub < 2; sub++)
    #pragma unroll
    for (int hb = 0; hb < 4; hb++)
      #pragma unroll
      for (int r = 0; r < 4; r++){
        long row = tokbase + q0 + sub * 64 + w * 16 + (lane >> 4) * 4 + r;
        float val = oa[sub][hb][r] / lacc[sub][r];
        og[row * 1024 + hd0 + hb * 16 + (lane & 15)] = (__bf16)val;
      }
}

// ---------------- GEMM: global_load_lds + XOR swizzle + 2-phase LDS double-buffer
// C[M,N] = A[M,K] @ Bt[N,K]^T, 128x128 tile, BK=64, 4 waves
// EPI: 0=store bf16, 1=gelu->bf16, 2=resid+gate*acc (f32), 4=atomicAdd(w*acc), 5=resid+gate*(acc+addin)
// GMODE: 0=linear, 1=expert GEMM1 (src=pair>>1, dst=pair), 2=expert GEMM2 (src=pair, dst=pair>>1)
template<int EPI, int GMODE>
__global__ __launch_bounds__(256)
void gemm_k(const __bf16* __restrict__ A, int lda,
            const __bf16* __restrict__ Bt, int K, long bstride,
            const int* __restrict__ lists, const int* __restrict__ counts,
            __bf16* __restrict__ outb, int ldo,
            float* __restrict__ outf,
            const float* __restrict__ resid,
            const float* __restrict__ mods, int mod_off,
            const float* __restrict__ wpair,
            const float* __restrict__ addin){
  int e = blockIdx.z;
  int cnt = 1 << 30;
  const int* list = nullptr;
  if (GMODE){
    cnt = counts[e];
    if ((int)blockIdx.y * 128 >= cnt) return;
    list = lists + e * 4096;
    Bt += (long)e * bstride;
  }
  int row0 = blockIdx.y * 128;
  int n0 = blockIdx.x * 128;
  int tid = threadIdx.x;
  int lane = tid & 63, w = tid >> 6;
  int wr = (w >> 1) * 64, wc = (w & 1) * 64;

  __shared__ __bf16 As[2 * 128 * 64];
  __shared__ __bf16 Bs[2 * 128 * 64];

  f32x4 acc[4][4];
  #pragma unroll
  for (int m = 0; m < 4; m++)
    #pragma unroll
    for (int n = 0; n < 4; n++) acc[m][n] = (f32x4){0.f, 0.f, 0.f, 0.f};

  long aoff[4]; const __bf16* bptr[4];
  #pragma unroll
  for (int j = 0; j < 4; j++){
    int r = w * 32 + j * 8 + (lane >> 3);
    int scb = (lane & 7) ^ (r & 7);
    int gr = row0 + r;
    int srcr;
    if (GMODE == 0) srcr = gr;
    else if (gr < cnt){ int pv = list[gr]; srcr = (GMODE == 1) ? (pv >> 1) : pv; }
    else { int pv = list[0]; srcr = (GMODE == 1) ? (pv >> 1) : pv; }  // harmless garbage row
    aoff[j] = (long)srcr * lda + scb * 8;
    bptr[j] = Bt + (long)(n0 + r) * K + scb * 8;
  }
  const int nk = K / 64;
  // prologue: stage tile 0 into buffer 0
  #pragma unroll
  for (int j = 0; j < 4; j++){
    gload_lds16(A + aoff[j], &As[(w * 32 + j * 8) * 64]);
    gload_lds16(bptr[j],     &Bs[(w * 32 + j * 8) * 64]);
  }
  __syncthreads();   // drains vmcnt: tile 0 resident
  int cur = 0;
  for (int kt = 0; kt < nk; ++kt){
    int nxt = cur ^ 1;
    if (kt + 1 < nk){
      int k0 = (kt + 1) * 64;
      #pragma unroll
      for (int j = 0; j < 4; j++){
        gload_lds16(A + aoff[j] + k0, &As[nxt * 8192 + (w * 32 + j * 8) * 64]);
        gload_lds16(bptr[j] + k0,     &Bs[nxt * 8192 + (w * 32 + j * 8) * 64]);
      }
    }
    #pragma unroll
    for (int ks = 0; ks < 2; ++ks){
      bf16x8 af[4], bfr[4];
      #pragma unroll
      for (int m = 0; m < 4; m++){
        int r = wr + m * 16 + (lane & 15);
        int blk = (ks * 4 + (lane >> 4)) ^ (r & 7);
        af[m] = *(const bf16x8*)&As[cur * 8192 + r * 64 + blk * 8];
      }
      #pragma unroll
      for (int n = 0; n < 4; n++){
        int r = wc + n * 16 + (lane & 15);
        int blk = (ks * 4 + (lane >> 4)) ^ (r & 7);
        bfr[n] = *(const bf16x8*)&Bs[cur * 8192 + r * 64 + blk * 8];
      }
      #pragma unroll
      for (int m = 0; m < 4; m++)
        #pragma unroll
        for (int n = 0; n < 4; n++)
          acc[m][n] = __builtin_amdgcn_mfma_f32_16x16x32_bf16(af[m], bfr[n], acc[m][n], 0, 0, 0);
    }
    __syncthreads();  // drains vmcnt(0)+lgkmcnt(0): next tile resident, cur free for overwrite
    cur = nxt;
  }
  #pragma unroll
  for (int m = 0; m < 4; m++){
    #pragma unroll
    for (int r = 0; r < 4; r++){
      int rl = wr + m * 16 + (lane >> 4) * 4 + r;
      int grow = row0 + rl;
      if (GMODE && grow >= cnt) continue;
      #pragma unroll
      for (int n = 0; n < 4; n++){
        int col = n0 + wc + n * 16 + (lane & 15);
        float v = acc[m][n][r];
        if (EPI == 0){
          outb[(long)grow * ldo + col] = (__bf16)v;
        } else if (EPI == 1){
          int dst = (GMODE == 1) ? list[grow] : grow;
          outb[(long)dst * ldo + col] = (__bf16)gelu_t(v);
        } else if (EPI == 2){
          int b = grow >> 10;
          outf[(long)grow * 1024 + col] = resid[(long)grow * 1024 + col] + mods[b * 6144 + mod_off + col] * v;
        } else if (EPI == 4){
          int pv = list[grow];
          atomicAdd(&outf[(long)(pv >> 1) * 1024 + col], wpair[pv] * v);
        } else if (EPI == 5){
          int b = grow >> 10;
          outf[(long)grow * 1024 + col] = resid[(long)grow * 1024 + col]
              + mods[b * 6144 + mod_off + col] * (v + addin[(long)grow * 1024 + col]);
        }
      }
    }
  }
}

extern "C" void kernel_launch(void* const* d_in, const int* in_sizes, int n_in,
                              void* d_out, int out_size, void* d_ws, size_t ws_size,
                              hipStream_t stream){
  const float* hidden = (const float*)d_in[0];
  const float* cond   = (const float*)d_in[1];
  const float* adaW   = (const float*)d_in[2];
  const float* ln1s   = (const float*)d_in[3];
  const float* ln1b   = (const float*)d_in[4];
  const float* ln2s   = (const float*)d_in[5];
  const float* ln2b   = (const float*)d_in[6];
  const float* Wq     = (const float*)d_in[7];
  const float* Wk     = (const float*)d_in[8];
  const float* Wv     = (const float*)d_in[9];
  const float* Wo     = (const float*)d_in[10];
  const float* gatek  = (const float*)d_in[11];
  const float* We1    = (const float*)d_in[12];
  const float* We2    = (const float*)d_in[13];
  const float* Ws1    = (const float*)d_in[14];
  const float* Ws2    = (const float*)d_in[15];
  float* out = (float*)d_out;

  const size_t MB = 1024 * 1024;
  char* W = (char*)d_ws;
  size_t off = 0;
  auto take = [&](size_t b) -> void* {
    void* p = W + off;
    off += (b + 255) & ~((size_t)255);
    return p;
  };
  float*  mods   = (float*) take(4 * 6144 * sizeof(float));  // 98304 B (256-mult)
  float*  yb     = (float*) take(16 * MB);                   // contiguous with mods: one memset
  __bf16* qkvT   = (__bf16*)take(6 * MB);   // [3072][1024]
  __bf16* WoT    = (__bf16*)take(2 * MB);
  __bf16* Ws1T   = (__bf16*)take(4 * MB);
  __bf16* Ws2T   = (__bf16*)take(4 * MB);
  __bf16* We1T   = (__bf16*)take(16 * MB);
  __bf16* We2T   = (__bf16*)take(16 * MB);
  __bf16* n1     = (__bf16*)take(8 * MB);   // [4096][1024]
  __bf16* ab     = (__bf16*)take(8 * MB);   // attn out; n1+ab contiguous = EH alias
  __bf16* qkv    = (__bf16*)take(24 * MB);  // [4096][3072]
  float*  hb     = (float*) take(16 * MB);
  __bf16* n2     = (__bf16*)take(8 * MB);
  int*    counts = (int*)   take(256);
  int*    lists  = (int*)   take(8 * 4096 * 4);
  float*  wpair  = (float*) take(8192 * 4);
  int*    eidx   = (int*)   take(8192 * 4);
  __bf16* EH = n1;   // [8192][1024] = 16 MB, aliases n1+ab (both dead by expert GEMM1)
  __bf16* SH = qkv;  // [4096][2048] = 16 MB, aliases qkv (dead after attention)

  dim3 blk(256);

  // zero mods + yb in one shot (contiguous)
  hipMemsetAsync(mods, 0, 4 * 6144 * sizeof(float) + 16 * MB, stream);

  // all weight transposes fp32 -> bf16 [N][K], one launch
  transpose_all<<<dim3(32, 32, 24), blk, 0, stream>>>(Wq, Wk, Wv, Wo, Ws1, Ws2, We1, We2,
                                                      qkvT, WoT, Ws1T, Ws2T, We1T, We2T);

  adaln_k<<<dim3(24, 4), blk, 0, stream>>>(cond, adaW, mods);

  // LN1 + modulate (shift_msa@0, scale_msa@1024)
  ln_mod<<<4096, blk, 0, stream>>>(hidden, ln1s, ln1b, mods, 0, 1024, n1);

  // fused QKV projection: [4096][3072]
  gemm_k<0, 0><<<dim3(24, 32, 1), blk, 0, stream>>>(n1, 1024, qkvT, 1024, 0, nullptr, nullptr, qkv, 3072, nullptr, nullptr, nullptr, 0, nullptr, nullptr);

  attn_k<<<dim3(8, 64, 1), blk, 0, stream>>>(qkv, ab);

  // h = hidden + gate_msa (mods@2048) * (attn @ Wo)
  gemm_k<2, 0><<<dim3(8, 32, 1), blk, 0, stream>>>(ab, 1024, WoT, 1024, 0, nullptr, nullptr, nullptr, 0, hb, hidden, mods, 2048, nullptr, nullptr);

  // MoE gate: fp32 LN2+modulate recompute -> n2 (bf16) + top2 routing
  gate_k<<<1024, blk, 0, stream>>>(hb, ln2s, ln2b, mods, gatek, eidx, wpair, n2);
  build_k<<<8, blk, 0, stream>>>(eidx, counts, lists);

  // routed experts (top-2 only): EH = gelu(gather(n2) @ We1[e]); yb += w * (EH @ We2[e])
  gemm_k<1, 1><<<dim3(8, 32, 8), blk, 0, stream>>>(n2, 1024, We1T, 1024, 1048576, lists, counts, EH, 1024, nullptr, nullptr, nullptr, 0, nullptr, nullptr);
  gemm_k<4, 2><<<dim3(8, 32, 8), blk, 0, stream>>>(EH, 1024, We2T, 1024, 1048576, lists, counts, nullptr, 0, yb, nullptr, nullptr, 0, wpair, nullptr);

  // shared experts: SH = gelu(n2 @ Ws1); out = hb + gate_mlp (mods@5120) * (SH @ Ws2 + yb)
  gemm_k<1, 0><<<dim3(16, 32, 1), blk, 0, stream>>>(n2, 1024, Ws1T, 1024, 0, nullptr, nullptr, SH, 2048, nullptr, nullptr, nullptr, 0, nullptr, nullptr);
  gemm_k<5, 0><<<dim3(8, 32, 1), blk, 0, stream>>>(SH, 2048, Ws2T, 2048, 0, nullptr, nullptr, nullptr, 0, out, hb, mods, 5120, nullptr, yb);

  (void)in_sizes; (void)n_in; (void)out_size; (void)ws_size;
}

// Round 6
// 484.348 us; speedup vs baseline: 1.6955x; 1.1580x over previous
//
#include <hip/hip_runtime.h>

typedef __bf16 bf16x8 __attribute__((ext_vector_type(8)));
typedef __bf16 bf16x4 __attribute__((ext_vector_type(4)));
typedef float  f32x4  __attribute__((ext_vector_type(4)));

__device__ inline float wred_sum(float v){
  #pragma unroll
  for (int d = 1; d < 64; d <<= 1) v += __shfl_xor(v, d, 64);
  return v;
}

__device__ inline float gelu_t(float x){
  const float c0 = 0.7978845608028654f;
  float t = tanhf(c0 * (x + 0.044715f * x * x * x));
  return 0.5f * x * (1.0f + t);
}

__device__ __forceinline__ void gload_lds16(const __bf16* g, __bf16* l){
  __builtin_amdgcn_global_load_lds((const __attribute__((address_space(1))) void*)g,
                                   (__attribute__((address_space(3))) void*)l, 16, 0, 0);
}

// ---------------- ALL weight transposes in one launch: 24 slabs of [1024][1024] f32 -> bf16^T
__global__ __launch_bounds__(256)
void transpose_all(const float* __restrict__ Wq, const float* __restrict__ Wk,
                   const float* __restrict__ Wv, const float* __restrict__ Wo,
                   const float* __restrict__ Ws1, const float* __restrict__ Ws2,
                   const float* __restrict__ We1, const float* __restrict__ We2,
                   __bf16* __restrict__ qkvT, __bf16* __restrict__ WoT,
                   __bf16* __restrict__ Ws1T, __bf16* __restrict__ Ws2T,
                   __bf16* __restrict__ We1T, __bf16* __restrict__ We2T){
  int z = blockIdx.z;
  const float* src; long ss; __bf16* dst; long ds;
  const long M1 = 1024 * 1024;
  if (z < 3)      { src = (z == 0 ? Wq : z == 1 ? Wk : Wv); ss = 1024; dst = qkvT + (long)z * M1; ds = 1024; }
  else if (z == 3){ src = Wo; ss = 1024; dst = WoT; ds = 1024; }
  else if (z < 6) { int ch = z - 4; src = Ws1 + ch * 1024; ss = 2048; dst = Ws1T + (long)ch * M1; ds = 1024; }
  else if (z < 8) { int rh = z - 6; src = Ws2 + (long)rh * M1; ss = 1024; dst = Ws2T + rh * 1024; ds = 2048; }
  else if (z < 16){ int e = z - 8;  src = We1 + (long)e * M1; ss = 1024; dst = We1T + (long)e * M1; ds = 1024; }
  else            { int e = z - 16; src = We2 + (long)e * M1; ss = 1024; dst = We2T + (long)e * M1; ds = 1024; }
  __shared__ float t[32][33];
  int r0 = blockIdx.y * 32, c0 = blockIdx.x * 32;
  int tid = threadIdx.x;
  int tr = tid >> 3, tc = (tid & 7) * 4;
  float4 vv = *(const float4*)&src[(long)(r0 + tr) * ss + c0 + tc];
  t[tr][tc + 0] = vv.x; t[tr][tc + 1] = vv.y; t[tr][tc + 2] = vv.z; t[tr][tc + 3] = vv.w;
  __syncthreads();
  int oc = tid >> 3, orr = (tid & 7) * 4;
  bf16x4 o4;
  #pragma unroll
  for (int i = 0; i < 4; i++) o4[i] = (__bf16)t[orr + i][oc];
  *(bf16x4*)&dst[(long)(c0 + oc) * ds + r0 + orr] = o4;
}

// ---------------- adaLN: split-K atomics, all 4 batches per W element (W read once)
__global__ __launch_bounds__(256)
void adaln_k(const float* __restrict__ cond, const float* __restrict__ W, float* __restrict__ mods){
  int col = blockIdx.x * 256 + threadIdx.x;
  int kc  = blockIdx.y;
  __shared__ float sc[4][256];
  for (int i = threadIdx.x; i < 1024; i += 256){
    int b = i >> 8, r = i & 255;
    float x = cond[b * 1024 + kc * 256 + r];
    sc[b][r] = x / (1.f + expf(-x));
  }
  __syncthreads();
  float a0 = 0.f, a1 = 0.f, a2 = 0.f, a3 = 0.f;
  #pragma unroll 4
  for (int i = 0; i < 256; i++){
    float wv = W[(long)(kc * 256 + i) * 6144 + col];
    a0 += sc[0][i] * wv; a1 += sc[1][i] * wv;
    a2 += sc[2][i] * wv; a3 += sc[3][i] * wv;
  }
  atomicAdd(&mods[0 * 6144 + col], a0);
  atomicAdd(&mods[1 * 6144 + col], a1);
  atomicAdd(&mods[2 * 6144 + col], a2);
  atomicAdd(&mods[3 * 6144 + col], a3);
}

// ---------------- LayerNorm + modulate -> bf16 (LN1)
__global__ __launch_bounds__(256)
void ln_mod(const float* __restrict__ x, const float* __restrict__ sc, const float* __restrict__ bi,
            const float* __restrict__ mods, int shift_off, int scale_off, __bf16* __restrict__ out){
  int row = blockIdx.x, tid = threadIdx.x, b = row >> 10;
  float4 xv = *(const float4*)&x[(long)row * 1024 + tid * 4];
  float s  = xv.x + xv.y + xv.z + xv.w;
  float s2 = xv.x * xv.x + xv.y * xv.y + xv.z * xv.z + xv.w * xv.w;
  s = wred_sum(s); s2 = wred_sum(s2);
  __shared__ float ssum[4], ssum2[4];
  int w = tid >> 6;
  if ((tid & 63) == 0){ ssum[w] = s; ssum2[w] = s2; }
  __syncthreads();
  s = ssum[0] + ssum[1] + ssum[2] + ssum[3];
  s2 = ssum2[0] + ssum2[1] + ssum2[2] + ssum2[3];
  float mean = s * (1.f / 1024.f);
  float var  = s2 * (1.f / 1024.f) - mean * mean;
  float inv  = rsqrtf(var + 1e-6f);
  const float xa[4] = {xv.x, xv.y, xv.z, xv.w};
  #pragma unroll
  for (int i = 0; i < 4; i++){
    int c = tid * 4 + i;
    float nv = (xa[i] - mean) * inv * sc[c] + bi[c];
    nv = nv * (1.f + mods[b * 6144 + scale_off + c]) + mods[b * 6144 + shift_off + c];
    out[(long)row * 1024 + c] = (__bf16)nv;
  }
}

// ---------------- gate: LN2 recompute in fp32, writes n2 (bf16) + top2 eidx/wpair. NO atomics.
__global__ __launch_bounds__(256)
void gate_k(const float* __restrict__ h, const float* __restrict__ ln2s, const float* __restrict__ ln2b,
            const float* __restrict__ mods, const float* __restrict__ gw,
            int* __restrict__ eidx, float* __restrict__ wpair, __bf16* __restrict__ n2o){
  __shared__ float gws[8192];
  int tid = threadIdx.x;
  #pragma unroll
  for (int i = 0; i < 8; i++){
    int idx = tid + i * 256;
    *(float4*)&gws[idx * 4] = *(const float4*)&gw[idx * 4];
  }
  __syncthreads();
  int wv = tid >> 6, lane = tid & 63;
  int tok = blockIdx.x * 4 + wv;
  int b = tok >> 10;
  float4 xv[4]; float s = 0.f, s2 = 0.f;
  #pragma unroll
  for (int ch = 0; ch < 4; ch++){
    float4 v = *(const float4*)&h[(long)tok * 1024 + ch * 256 + lane * 4];
    xv[ch] = v;
    s  += v.x + v.y + v.z + v.w;
    s2 += v.x * v.x + v.y * v.y + v.z * v.z + v.w * v.w;
  }
  s = wred_sum(s); s2 = wred_sum(s2);
  float mean = s * (1.f / 1024.f);
  float var  = s2 * (1.f / 1024.f) - mean * mean;
  float inv  = rsqrtf(var + 1e-6f);
  float lg[8];
  #pragma unroll
  for (int e = 0; e < 8; e++) lg[e] = 0.f;
  #pragma unroll
  for (int ch = 0; ch < 4; ch++){
    int c = ch * 256 + lane * 4;
    float4 s4  = *(const float4*)&ln2s[c];
    float4 b4  = *(const float4*)&ln2b[c];
    float4 sc4 = *(const float4*)&mods[b * 6144 + 4096 + c];
    float4 sh4 = *(const float4*)&mods[b * 6144 + 3072 + c];
    float v0 = ((xv[ch].x - mean) * inv * s4.x + b4.x) * (1.f + sc4.x) + sh4.x;
    float v1 = ((xv[ch].y - mean) * inv * s4.y + b4.y) * (1.f + sc4.y) + sh4.y;
    float v2 = ((xv[ch].z - mean) * inv * s4.z + b4.z) * (1.f + sc4.z) + sh4.z;
    float v3 = ((xv[ch].w - mean) * inv * s4.w + b4.w) * (1.f + sc4.w) + sh4.w;
    *(bf16x4*)&n2o[(long)tok * 1024 + c] = (bf16x4){(__bf16)v0, (__bf16)v1, (__bf16)v2, (__bf16)v3};
    #pragma unroll
    for (int e = 0; e < 8; e++){
      float4 g4 = *(const float4*)&gws[e * 1024 + c];
      lg[e] += v0 * g4.x + v1 * g4.y + v2 * g4.z + v3 * g4.w;
    }
  }
  #pragma unroll
  for (int e = 0; e < 8; e++) lg[e] = wred_sum(lg[e]);
  if (lane == 0){
    float mx = lg[0];
    #pragma unroll
    for (int e = 1; e < 8; e++) mx = fmaxf(mx, lg[e]);
    float p[8], ss = 0.f;
    #pragma unroll
    for (int e = 0; e < 8; e++){ p[e] = expf(lg[e] - mx); ss += p[e]; }
    #pragma unroll
    for (int e = 0; e < 8; e++) p[e] /= ss;
    int i0 = 0; float b0 = p[0];
    #pragma unroll
    for (int e = 1; e < 8; e++) if (p[e] > b0){ b0 = p[e]; i0 = e; }
    int i1 = -1; float b1 = -1.f;
    #pragma unroll
    for (int e = 0; e < 8; e++) if (e != i0 && p[e] > b1){ b1 = p[e]; i1 = e; }
    float dn = b0 + b1 + 1e-20f;
    eidx[tok * 2]     = i0; wpair[tok * 2]     = b0 / dn;
    eidx[tok * 2 + 1] = i1; wpair[tok * 2 + 1] = b1 / dn;
  }
}

// ---------------- build routing lists: 1 block per expert, ordered ballot compaction
__global__ __launch_bounds__(256)
void build_k(const int* __restrict__ eidx, int* __restrict__ counts, int* __restrict__ lists){
  int e = blockIdx.x;
  int tid = threadIdx.x, wv = tid >> 6, lane = tid & 63;
  __shared__ int base;
  __shared__ int woff[4];
  if (tid == 0) base = 0;
  __syncthreads();
  for (int it = 0; it < 32; ++it){
    int i = it * 256 + tid;
    bool m = (eidx[i] == e);
    unsigned long long bal = __ballot(m);
    int prefix = __popcll(bal & ((1ull << lane) - 1ull));
    if (lane == 0) woff[wv] = __popcll(bal);
    __syncthreads();
    int off = base;
    #pragma unroll
    for (int k = 0; k < 4; k++) if (k < wv) off += woff[k];
    if (m) lists[e * 4096 + off + prefix] = i;
    __syncthreads();
    if (tid == 0) base += woff[0] + woff[1] + woff[2] + woff[3];
    __syncthreads();
  }
  if (tid == 0) counts[e] = base;
}

// ---------------- flash attention: 128 q-rows/block, XCD-grouped (b,h), exp2+defer-max
__global__ __launch_bounds__(256)
void attn_k(const __bf16* __restrict__ qkv, __bf16* __restrict__ og){
  int p = blockIdx.x + blockIdx.y * 8;          // gridDim.x == 8
  int qblk = (p >> 3) & 7;
  int bh   = (p & 7) + ((p >> 6) << 3);
  int bb = bh >> 4, hn = bh & 15;
  int q0 = qblk * 128;
  long tokbase = (long)bb * 1024;
  int hd0 = hn * 64;
  int tid = threadIdx.x; int w = tid >> 6; int lane = tid & 63;

  __shared__ __bf16 Ks[64][76];
  __shared__ __bf16 Vt[64][76];
  __shared__ __bf16 Ps[4][32][76];

  const float QS = 0.125f * 1.44269504088896f;
  bf16x8 qf[2][2];
  #pragma unroll
  for (int sub = 0; sub < 2; sub++){
    long qrow = tokbase + q0 + sub * 64 + w * 16 + (lane & 15);
    qf[sub][0] = *(const bf16x8*)&qkv[qrow * 3072 + hd0 + (lane >> 4) * 8];
    qf[sub][1] = *(const bf16x8*)&qkv[qrow * 3072 + hd0 + 32 + (lane >> 4) * 8];
    #pragma unroll
    for (int i = 0; i < 8; i++){
      qf[sub][0][i] = (__bf16)((float)qf[sub][0][i] * QS);
      qf[sub][1][i] = (__bf16)((float)qf[sub][1][i] * QS);
    }
  }

  __bf16 one_b = (__bf16)1.0f;
  bf16x8 one8 = (bf16x8){one_b, one_b, one_b, one_b, one_b, one_b, one_b, one_b};

  float m_r[2][4];
  f32x4 oa[2][4];
  f32x4 lacc[2];
  #pragma unroll
  for (int sub = 0; sub < 2; sub++){
    lacc[sub] = (f32x4){0.f, 0.f, 0.f, 0.f};
    #pragma unroll
    for (int r = 0; r < 4; r++) m_r[sub][r] = -1e30f;
    #pragma unroll
    for (int hb = 0; hb < 4; hb++) oa[sub][hb] = (f32x4){0.f, 0.f, 0.f, 0.f};
  }

  int dcol = tid & 63, rblk = tid >> 6;
  for (int t = 0; t < 16; t++){
    long kvbase = tokbase + t * 64;
    #pragma unroll
    for (int pp = 0; pp < 2; pp++){
      int r = (tid >> 3) + pp * 32;
      int c = (tid & 7) * 8;
      *(bf16x8*)&Ks[r][c] = *(const bf16x8*)&qkv[(kvbase + r) * 3072 + 1024 + hd0 + c];
    }
    bf16x8 col0, col1;
    #pragma unroll
    for (int i = 0; i < 8; i++)
      col0[i] = qkv[(kvbase + rblk * 16 + i) * 3072 + 2048 + hd0 + dcol];
    #pragma unroll
    for (int i = 0; i < 8; i++)
      col1[i] = qkv[(kvbase + rblk * 16 + 8 + i) * 3072 + 2048 + hd0 + dcol];
    *(bf16x8*)&Vt[dcol][rblk * 16]     = col0;
    *(bf16x8*)&Vt[dcol][rblk * 16 + 8] = col1;
    __syncthreads();

    #pragma unroll
    for (int sub = 0; sub < 2; sub++){
      f32x4 sf[4];
      #pragma unroll
      for (int cb = 0; cb < 4; cb++){
        bf16x8 kf0 = *(const bf16x8*)&Ks[cb * 16 + (lane & 15)][(lane >> 4) * 8];
        bf16x8 kf1 = *(const bf16x8*)&Ks[cb * 16 + (lane & 15)][32 + (lane >> 4) * 8];
        f32x4 sacc = (f32x4){0.f, 0.f, 0.f, 0.f};
        sacc = __builtin_amdgcn_mfma_f32_16x16x32_bf16(qf[sub][0], kf0, sacc, 0, 0, 0);
        sacc = __builtin_amdgcn_mfma_f32_16x16x32_bf16(qf[sub][1], kf1, sacc, 0, 0, 0);
        sf[cb] = sacc;
      }
      float mxr[4]; float dmax = -1e30f;
      #pragma unroll
      for (int r = 0; r < 4; r++){
        float mx = fmaxf(fmaxf(sf[0][r], sf[1][r]), fmaxf(sf[2][r], sf[3][r]));
        #pragma unroll
        for (int d = 1; d < 16; d <<= 1) mx = fmaxf(mx, __shfl_xor(mx, d, 64));
        mxr[r] = mx;
        dmax = fmaxf(dmax, mx - m_r[sub][r]);
      }
      if (!__all(dmax <= 8.f)){
        #pragma unroll
        for (int r = 0; r < 4; r++){
          float mn = fmaxf(m_r[sub][r], mxr[r]);
          float fr = __builtin_amdgcn_exp2f(m_r[sub][r] - mn);
          m_r[sub][r] = mn;
          lacc[sub][r] *= fr;
          #pragma unroll
          for (int hb = 0; hb < 4; hb++) oa[sub][hb][r] *= fr;
        }
      }
      #pragma unroll
      for (int cb = 0; cb < 4; cb++)
        #pragma unroll
        for (int r = 0; r < 4; r++)
          Ps[w][sub * 16 + (lane >> 4) * 4 + r][cb * 16 + (lane & 15)] =
            (__bf16)__builtin_amdgcn_exp2f(sf[cb][r] - m_r[sub][r]);
    }
    bf16x8 pf[2][2];
    #pragma unroll
    for (int sub = 0; sub < 2; sub++){
      pf[sub][0] = *(const bf16x8*)&Ps[w][sub * 16 + (lane & 15)][(lane >> 4) * 8];
      pf[sub][1] = *(const bf16x8*)&Ps[w][sub * 16 + (lane & 15)][32 + (lane >> 4) * 8];
      lacc[sub] = __builtin_amdgcn_mfma_f32_16x16x32_bf16(pf[sub][0], one8, lacc[sub], 0, 0, 0);
      lacc[sub] = __builtin_amdgcn_mfma_f32_16x16x32_bf16(pf[sub][1], one8, lacc[sub], 0, 0, 0);
    }
    #pragma unroll
    for (int hb = 0; hb < 4; hb++){
      bf16x8 vf0 = *(const bf16x8*)&Vt[hb * 16 + (lane & 15)][(lane >> 4) * 8];
      bf16x8 vf1 = *(const bf16x8*)&Vt[hb * 16 + (lane & 15)][32 + (lane >> 4) * 8];
      #pragma unroll
      for (int sub = 0; sub < 2; sub++){
        oa[sub][hb] = __builtin_amdgcn_mfma_f32_16x16x32_bf16(pf[sub][0], vf0, oa[sub][hb], 0, 0, 0);
        oa[sub][hb] = __builtin_amdgcn_mfma_f32_16x16x32_bf16(pf[sub][1], vf1, oa[sub][hb], 0, 0, 0);
      }
    }
    __syncthreads();
  }
  #pragma unroll
  for (int sub = 0; sub < 2; sub++)
    #pragma unroll
    for (int hb = 0; hb < 4; hb++)
      #pragma unroll
      for (int r = 0; r < 4; r++){
        long row = tokbase + q0 + sub * 64 + w * 16 + (lane >> 4) * 4 + r;
        float val = oa[sub][hb][r] / lacc[sub][r];
        og[row * 1024 + hd0 + hb * 16 + (lane & 15)] = (__bf16)val;
      }
}

// ---------------- GEMM: 512 threads / 8 waves (2Mx4N), single-buffer 32KB LDS,
// global_load_lds + XOR swizzle. C[M,N] = A[M,K] @ Bt[N,K]^T, 128x128 tile, BK=64.
// EPI: 0=store bf16, 1=gelu->bf16, 2=resid+gate*acc (f32), 5=resid+gate*(acc+EO2t+EO2t1), 6=EO[pv]=w*acc
// GMODE: 0=linear, 2=expert GEMM2 (src=pair), 3=combined GEMM1 (z<8 routed, z>=8 shared halves)
template<int EPI, int GMODE>
__global__ __launch_bounds__(512)
void gemm_k(const __bf16* __restrict__ A, int lda,
            const __bf16* __restrict__ Bt, int K, long bstride,
            const __bf16* __restrict__ Bt2,
            const int* __restrict__ lists, const int* __restrict__ counts,
            __bf16* __restrict__ outb, int ldo,
            __bf16* __restrict__ outb2, int ldo2,
            float* __restrict__ outf,
            const float* __restrict__ resid,
            const float* __restrict__ mods, int mod_off,
            const float* __restrict__ wpair,
            const __bf16* __restrict__ eo){
  int z = blockIdx.z;
  int cnt = 1 << 30;
  const int* list = nullptr;
  const __bf16* B = Bt;
  __bf16* OB = outb; int LDO = ldo;
  bool shp = false;
  if (GMODE == 2){
    cnt = counts[z];
    if ((int)blockIdx.y * 128 >= cnt) return;
    list = lists + z * 4096;
    B = Bt + (long)z * bstride;
  } else if (GMODE == 3){
    if (z < 8){
      cnt = counts[z];
      if ((int)blockIdx.y * 128 >= cnt) return;
      list = lists + z * 4096;
      B = Bt + (long)z * bstride;
    } else {
      shp = true;
      B = Bt2 + (long)(z - 8) * bstride;
      OB = outb2 + (long)(z - 8) * 1024; LDO = ldo2;
    }
  }
  int row0 = blockIdx.y * 128;
  int n0 = blockIdx.x * 128;
  int tid = threadIdx.x;
  int lane = tid & 63, w = tid >> 6;
  int wr = (w >> 2) * 64, wc = (w & 3) * 32;

  __shared__ __bf16 As[128 * 64];
  __shared__ __bf16 Bs[128 * 64];

  f32x4 acc[4][2];
  #pragma unroll
  for (int m = 0; m < 4; m++)
    #pragma unroll
    for (int n = 0; n < 2; n++) acc[m][n] = (f32x4){0.f, 0.f, 0.f, 0.f};

  // staging: call j covers rows [j*64 + w*8, +8); lane l -> row +(l>>3), col-block (l&7)^(row&7)
  long aoff[2]; const __bf16* bptr[2];
  #pragma unroll
  for (int j = 0; j < 2; j++){
    int r = j * 64 + w * 8 + (lane >> 3);
    int scb = (lane & 7) ^ (r & 7);
    int gr = row0 + r;
    int srcr;
    bool routed = (GMODE == 2) || (GMODE == 3 && !shp);
    if (!routed) srcr = gr;
    else if (gr < cnt){ int pv = list[gr]; srcr = (GMODE == 3) ? (pv >> 1) : pv; }
    else { int pv = list[0]; srcr = (GMODE == 3) ? (pv >> 1) : pv; }
    aoff[j] = (long)srcr * lda + scb * 8;
    bptr[j] = B + (long)(n0 + r) * K + scb * 8;
  }
  const int nk = K / 64;
  for (int kt = 0; kt < nk; ++kt){
    int k0 = kt * 64;
    #pragma unroll
    for (int j = 0; j < 2; j++){
      gload_lds16(A + aoff[j] + k0, &As[(j * 64 + w * 8) * 64]);
      gload_lds16(bptr[j] + k0,     &Bs[(j * 64 + w * 8) * 64]);
    }
    __syncthreads();
    #pragma unroll
    for (int ks = 0; ks < 2; ++ks){
      bf16x8 af[4], bfr[2];
      #pragma unroll
      for (int m = 0; m < 4; m++){
        int r = wr + m * 16 + (lane & 15);
        int blk = (ks * 4 + (lane >> 4)) ^ (r & 7);
        af[m] = *(const bf16x8*)&As[r * 64 + blk * 8];
      }
      #pragma unroll
      for (int n = 0; n < 2; n++){
        int r = wc + n * 16 + (lane & 15);
        int blk = (ks * 4 + (lane >> 4)) ^ (r & 7);
        bfr[n] = *(const bf16x8*)&Bs[r * 64 + blk * 8];
      }
      #pragma unroll
      for (int m = 0; m < 4; m++)
        #pragma unroll
        for (int n = 0; n < 2; n++)
          acc[m][n] = __builtin_amdgcn_mfma_f32_16x16x32_bf16(af[m], bfr[n], acc[m][n], 0, 0, 0);
    }
    __syncthreads();
  }
  #pragma unroll
  for (int m = 0; m < 4; m++){
    #pragma unroll
    for (int r = 0; r < 4; r++){
      int rl = wr + m * 16 + (lane >> 4) * 4 + r;
      int grow = row0 + rl;
      if ((GMODE == 2 || (GMODE == 3 && !shp)) && grow >= cnt) continue;
      #pragma unroll
      for (int n = 0; n < 2; n++){
        int col = n0 + wc + n * 16 + (lane & 15);
        float v = acc[m][n][r];
        if (EPI == 0){
          OB[(long)grow * LDO + col] = (__bf16)v;
        } else if (EPI == 1){
          int dst = (GMODE == 3 && !shp) ? list[grow] : grow;
          OB[(long)dst * LDO + col] = (__bf16)gelu_t(v);
        } else if (EPI == 2){
          int b = grow >> 10;
          outf[(long)grow * 1024 + col] = resid[(long)grow * 1024 + col] + mods[b * 6144 + mod_off + col] * v;
        } else if (EPI == 5){
          int b = grow >> 10;
          float add = (float)eo[(long)(grow * 2) * 1024 + col] + (float)eo[(long)(grow * 2 + 1) * 1024 + col];
          outf[(long)grow * 1024 + col] = resid[(long)grow * 1024 + col]
              + mods[b * 6144 + mod_off + col] * (v + add);
        } else if (EPI == 6){
          int pv = list[grow];
          OB[(long)pv * LDO + col] = (__bf16)(wpair[pv] * v);
        }
      }
    }
  }
}

extern "C" void kernel_launch(void* const* d_in, const int* in_sizes, int n_in,
                              void* d_out, int out_size, void* d_ws, size_t ws_size,
                              hipStream_t stream){
  const float* hidden = (const float*)d_in[0];
  const float* cond   = (const float*)d_in[1];
  const float* adaW   = (const float*)d_in[2];
  const float* ln1s   = (const float*)d_in[3];
  const float* ln1b   = (const float*)d_in[4];
  const float* ln2s   = (const float*)d_in[5];
  const float* ln2b   = (const float*)d_in[6];
  const float* Wq     = (const float*)d_in[7];
  const float* Wk     = (const float*)d_in[8];
  const float* Wv     = (const float*)d_in[9];
  const float* Wo     = (const float*)d_in[10];
  const float* gatek  = (const float*)d_in[11];
  const float* We1    = (const float*)d_in[12];
  const float* We2    = (const float*)d_in[13];
  const float* Ws1    = (const float*)d_in[14];
  const float* Ws2    = (const float*)d_in[15];
  float* out = (float*)d_out;

  const size_t MB = 1024 * 1024;
  char* W = (char*)d_ws;
  size_t off = 0;
  auto take = [&](size_t b) -> void* {
    void* p = W + off;
    off += (b + 255) & ~((size_t)255);
    return p;
  };
  float*  mods   = (float*) take(4 * 6144 * sizeof(float));
  __bf16* EO     = (__bf16*)take(16 * MB);  // [8192][1024] weighted expert outputs (every slot written once)
  __bf16* qkvT   = (__bf16*)take(6 * MB);   // [3072][1024]
  __bf16* WoT    = (__bf16*)take(2 * MB);
  __bf16* Ws1T   = (__bf16*)take(4 * MB);
  __bf16* Ws2T   = (__bf16*)take(4 * MB);
  __bf16* We1T   = (__bf16*)take(16 * MB);
  __bf16* We2T   = (__bf16*)take(16 * MB);
  __bf16* n1     = (__bf16*)take(8 * MB);   // [4096][1024]
  __bf16* ab     = (__bf16*)take(8 * MB);   // attn out; n1+ab contiguous = EH alias
  __bf16* qkv    = (__bf16*)take(24 * MB);  // [4096][3072]
  float*  hb     = (float*) take(16 * MB);
  __bf16* n2     = (__bf16*)take(8 * MB);
  int*    counts = (int*)   take(256);
  int*    lists  = (int*)   take(8 * 4096 * 4);
  float*  wpair  = (float*) take(8192 * 4);
  int*    eidx   = (int*)   take(8192 * 4);
  __bf16* EH = n1;   // [8192][1024] = 16 MB, aliases n1+ab (both dead by expert GEMM1)
  __bf16* SH = qkv;  // [4096][2048] = 16 MB, aliases qkv (dead after attention)

  dim3 blk(256), blk5(512);

  hipMemsetAsync(mods, 0, 4 * 6144 * sizeof(float), stream);

  transpose_all<<<dim3(32, 32, 24), blk, 0, stream>>>(Wq, Wk, Wv, Wo, Ws1, Ws2, We1, We2,
                                                      qkvT, WoT, Ws1T, Ws2T, We1T, We2T);

  adaln_k<<<dim3(24, 4), blk, 0, stream>>>(cond, adaW, mods);

  // LN1 + modulate (shift_msa@0, scale_msa@1024)
  ln_mod<<<4096, blk, 0, stream>>>(hidden, ln1s, ln1b, mods, 0, 1024, n1);

  // fused QKV projection: [4096][3072]
  gemm_k<0, 0><<<dim3(24, 32, 1), blk5, 0, stream>>>(n1, 1024, qkvT, 1024, 0, nullptr, nullptr, nullptr,
      qkv, 3072, nullptr, 0, nullptr, nullptr, nullptr, 0, nullptr, nullptr);

  attn_k<<<dim3(8, 64, 1), blk, 0, stream>>>(qkv, ab);

  // h = hidden + gate_msa (mods@2048) * (attn @ Wo)
  gemm_k<2, 0><<<dim3(8, 32, 1), blk5, 0, stream>>>(ab, 1024, WoT, 1024, 0, nullptr, nullptr, nullptr,
      nullptr, 0, nullptr, 0, hb, hidden, mods, 2048, nullptr, nullptr);

  // MoE gate: fp32 LN2+modulate recompute -> n2 (bf16) + top2 routing
  gate_k<<<1024, blk, 0, stream>>>(hb, ln2s, ln2b, mods, gatek, eidx, wpair, n2);
  build_k<<<8, blk, 0, stream>>>(eidx, counts, lists);

  // combined GEMM1: z<8 routed EH[pv] = gelu(gather(n2) @ We1[z]); z=8,9 SH halves = gelu(n2 @ Ws1)
  gemm_k<1, 3><<<dim3(8, 32, 10), blk5, 0, stream>>>(n2, 1024, We1T, 1024, 1048576, Ws1T, lists, counts,
      EH, 1024, SH, 2048, nullptr, nullptr, nullptr, 0, nullptr, nullptr);

  // expert GEMM2: EO[pv] = wpair[pv] * (EH[pv] @ We2[z])  — dense stores, no atomics
  gemm_k<6, 2><<<dim3(8, 32, 8), blk5, 0, stream>>>(EH, 1024, We2T, 1024, 1048576, nullptr, lists, counts,
      EO, 1024, nullptr, 0, nullptr, nullptr, nullptr, 0, wpair, nullptr);

  // shared GEMM2 + final combine: out = hb + gate_mlp (mods@5120) * (SH @ Ws2 + EO[2t] + EO[2t+1])
  gemm_k<5, 0><<<dim3(8, 32, 1), blk5, 0, stream>>>(SH, 2048, Ws2T, 2048, 0, nullptr, nullptr, nullptr,
      nullptr, 0, nullptr, 0, out, hb, mods, 5120, nullptr, EO);

  (void)in_sizes; (void)n_in; (void)out_size; (void)ws_size;
}